// Round 8
// baseline (613.236 us; speedup 1.0000x reference)
//
#include <hip/hip_runtime.h>
#include <hip/hip_bf16.h>
#include <math.h>

#define HIDDEN 4096
#define NH 32
#define NKV 8
#define HD 128
#define S_LEN 2048
#define BATCH 2
#define MROWS (BATCH * S_LEN)  // 4096
#define QKVW 6144              // fused q|k|v row width

typedef __attribute__((ext_vector_type(8))) __bf16 bf16x8;
typedef __attribute__((ext_vector_type(4))) float f32x4;

__device__ __forceinline__ f32x4 mfma16(bf16x8 a, bf16x8 b, f32x4 c) {
  return __builtin_amdgcn_mfma_f32_16x16x32_bf16(a, b, c, 0, 0, 0);
}

// async global->LDS, 16B/lane; LDS dest = wave-uniform base, HW adds lane*16.
__device__ __forceinline__ void gload16(const __bf16* g, const __bf16* l) {
  __builtin_amdgcn_global_load_lds(
      (const __attribute__((address_space(1))) void*)g,
      (__attribute__((address_space(3))) void*)l, 16, 0, 0);
}

#define SBAR()                          \
  do {                                  \
    __builtin_amdgcn_sched_barrier(0);  \
    __builtin_amdgcn_s_barrier();       \
    __builtin_amdgcn_sched_barrier(0);  \
  } while (0)

// ---------------------------------------------------------------------------
// fp32 -> bf16 elementwise convert (vectorized)
// ---------------------------------------------------------------------------
__global__ __launch_bounds__(256) void cvt_kernel(const float* __restrict__ in,
                                                  __bf16* __restrict__ out, int n) {
  int i = (blockIdx.x * 256 + threadIdx.x) * 8;
  if (i >= n) return;
  float4 a = *reinterpret_cast<const float4*>(in + i);
  float4 b = *reinterpret_cast<const float4*>(in + i + 4);
  bf16x8 t;
  t[0] = (__bf16)a.x; t[1] = (__bf16)a.y; t[2] = (__bf16)a.z; t[3] = (__bf16)a.w;
  t[4] = (__bf16)b.x; t[5] = (__bf16)b.y; t[6] = (__bf16)b.z; t[7] = (__bf16)b.w;
  *reinterpret_cast<bf16x8*>(out + i) = t;
}

// ---------------------------------------------------------------------------
// Fused weight transpose+convert: z=0 Wq (4096 cols), z=1 Wk, z=2 Wv (1024).
// ---------------------------------------------------------------------------
__global__ __launch_bounds__(256) void tcvt3_kernel(const float* __restrict__ Wq,
                                                    const float* __restrict__ Wk,
                                                    const float* __restrict__ Wv,
                                                    __bf16* __restrict__ Wt) {
  __shared__ float t[32][33];
  int z = blockIdx.z;
  const float* in;
  __bf16* out;
  int C;
  if (z == 0)      { in = Wq; out = Wt;                         C = 4096; }
  else if (z == 1) { in = Wk; out = Wt + (size_t)4096 * 4096;   C = 1024; }
  else             { in = Wv; out = Wt + (size_t)5120 * 4096;   C = 1024; }
  if ((int)blockIdx.x * 32 >= C) return;
  int tx = threadIdx.x, ty = threadIdx.y;
  int r0 = blockIdx.y * 32, c0 = blockIdx.x * 32;
#pragma unroll
  for (int i = 0; i < 4; i++)
    t[ty + i * 8][tx] = in[(size_t)(r0 + ty + i * 8) * C + c0 + tx];
  __syncthreads();
#pragma unroll
  for (int i = 0; i < 4; i++)
    out[(size_t)(c0 + ty + i * 8) * 4096 + r0 + tx] = (__bf16)t[tx][ty + i * 8];
}

// single transpose for Wo
__global__ __launch_bounds__(256) void tcvt_f32(const float* __restrict__ in,
                                                __bf16* __restrict__ out,
                                                int R, int C) {
  __shared__ float t[32][33];
  int tx = threadIdx.x, ty = threadIdx.y;
  int r0 = blockIdx.y * 32, c0 = blockIdx.x * 32;
#pragma unroll
  for (int i = 0; i < 4; i++)
    t[ty + i * 8][tx] = in[(size_t)(r0 + ty + i * 8) * C + c0 + tx];
  __syncthreads();
#pragma unroll
  for (int i = 0; i < 4; i++)
    out[(size_t)(c0 + ty + i * 8) * R + r0 + tx] = (__bf16)t[tx][ty + i * 8];
}

// ---------------------------------------------------------------------------
// V transpose: qkv [B*S][QKVW] (v at col 5120 + kvh*HD) -> vt [B*NKV][HD][S].
// ---------------------------------------------------------------------------
__global__ __launch_bounds__(256) void tvt_kernel(const __bf16* __restrict__ qkv,
                                                  __bf16* __restrict__ vt) {
  __shared__ __bf16 t[32][33];
  int tx = threadIdx.x, ty = threadIdx.y;
  int z = blockIdx.z;
  int b = z >> 3, kvh = z & 7;
  int kv0 = blockIdx.y * 32, d0 = blockIdx.x * 32;
#pragma unroll
  for (int i = 0; i < 4; i++)
    t[ty + i * 8][tx] =
        qkv[(size_t)(b * S_LEN + kv0 + ty + i * 8) * QKVW + 5120 + kvh * HD + d0 + tx];
  __syncthreads();
#pragma unroll
  for (int i = 0; i < 4; i++)
    vt[((size_t)z * HD + d0 + ty + i * 8) * S_LEN + kv0 + tx] = t[tx][ty + i * 8];
}

// ---------------------------------------------------------------------------
// 256x256 8-phase GEMM (m201-style): C[M,N] = A * Bt^T, ldc-strided output.
// ---------------------------------------------------------------------------
template<typename CT>
__global__ __launch_bounds__(512, 2) void gemm256(const __bf16* __restrict__ A,
                                                  const __bf16* __restrict__ Bt,
                                                  CT* __restrict__ C,
                                                  int K, int ldc, int nbx) {
  __shared__ char lds[131072];
  const int tid = threadIdx.x;
  const int l = tid & 63, w = tid >> 6;
  const int lrow = l & 15, lg = l >> 4;
  const int sw = (lrow & 7) << 4;

  int nwg = gridDim.x;
  int swz = (blockIdx.x & 7) * (nwg >> 3) + (blockIdx.x >> 3);
  int bx = swz % nbx, by = swz / nbx;
  int m0 = by * 256, n0 = bx * 256;

  const int rA = w * 8 + (l >> 3);
  const int csw = ((l & 7) ^ (l >> 3)) * 8;  // inverse-swizzled source col
  const __bf16* As_[2][2];
  const __bf16* Bs_[2][2];
#pragma unroll
  for (int h = 0; h < 2; h++)
#pragma unroll
    for (int p = 0; p < 2; p++) {
      As_[h][p] = A + (size_t)(m0 + h * 128 + p * 64 + rA) * K + csw;
      Bs_[h][p] = Bt + (size_t)(n0 + h * 128 + p * 64 + rA) * K + csw;
    }

  auto stageA = [&](int par, int h, int kt) {
#pragma unroll
    for (int p = 0; p < 2; p++)
      gload16(As_[h][p] + kt * 64,
              (const __bf16*)(lds + par * 32768 + h * 16384 + p * 8192 + w * 1024));
  };
  auto stageB = [&](int par, int h, int kt) {
#pragma unroll
    for (int p = 0; p < 2; p++)
      gload16(Bs_[h][p] + kt * 64,
              (const __bf16*)(lds + 65536 + par * 32768 + h * 16384 + p * 8192 + w * 1024));
  };

  const int arbase = (w >> 2) * 64 + lrow;
  const int brbase = (w & 3) * 32 + lrow;

  bf16x8 aA[4][2];
  bf16x8 bB[2][2][2];

  auto readA = [&](int par, int ah) {
#pragma unroll
    for (int i = 0; i < 4; i++)
#pragma unroll
      for (int kk = 0; kk < 2; kk++)
        aA[i][kk] = *reinterpret_cast<const bf16x8*>(
            lds + par * 32768 + (arbase + i * 16 + ah * 128) * 128 +
            ((kk * 64 + lg * 16) ^ sw));
  };
  auto readB = [&](int par, int bh) {
#pragma unroll
    for (int j = 0; j < 2; j++)
#pragma unroll
      for (int kk = 0; kk < 2; kk++)
        bB[bh][j][kk] = *reinterpret_cast<const bf16x8*>(
            lds + 65536 + par * 32768 + (brbase + j * 16 + bh * 128) * 128 +
            ((kk * 64 + lg * 16) ^ sw));
  };

  f32x4 acc[8][4];
#pragma unroll
  for (int i = 0; i < 8; i++)
#pragma unroll
    for (int j = 0; j < 4; j++) {
      acc[i][j][0] = 0.f; acc[i][j][1] = 0.f; acc[i][j][2] = 0.f; acc[i][j][3] = 0.f;
    }

  const int NT = K >> 6;

  stageA(0, 0, 0); stageA(0, 1, 0); stageB(0, 0, 0); stageB(0, 1, 0);
  stageA(1, 0, 1); stageB(1, 0, 1);
  __builtin_amdgcn_sched_barrier(0);
  asm volatile("s_waitcnt vmcnt(4)" ::: "memory");
  SBAR();

  for (int t = 0; t < NT; t++) {
    const int par = t & 1, npar = par ^ 1;
    const int t1 = (t + 1 < NT) ? t + 1 : 0;
    const int t2 = (t + 2 < NT) ? t + 2 : 0;

#define MFMA_QUAD(AH, BH)                                                   \
  __builtin_amdgcn_s_setprio(1);                                            \
  _Pragma("unroll") for (int i4 = 0; i4 < 4; i4++)                          \
      _Pragma("unroll") for (int j2 = 0; j2 < 2; j2++)                      \
          _Pragma("unroll") for (int kk = 0; kk < 2; kk++)                  \
              acc[(AH)*4 + i4][(BH)*2 + j2] =                               \
                  mfma16(aA[i4][kk], bB[BH][j2][kk], acc[(AH)*4 + i4][(BH)*2 + j2]); \
  __builtin_amdgcn_s_setprio(0);

    readA(par, 0);
    readB(par, 0);
    stageA(npar, 1, t1);
    SBAR();
    MFMA_QUAD(0, 0);
    SBAR();
    readB(par, 1);
    stageB(npar, 1, t1);
    SBAR();
    MFMA_QUAD(0, 1);
    SBAR();
    readA(par, 1);
    stageA(par, 0, t2);
    SBAR();
    MFMA_QUAD(1, 0);
    SBAR();
    stageB(par, 0, t2);
    SBAR();
    MFMA_QUAD(1, 1);
    __builtin_amdgcn_sched_barrier(0);
    asm volatile("s_waitcnt vmcnt(4)" ::: "memory");
    SBAR();
#undef MFMA_QUAD
  }

#pragma unroll
  for (int i = 0; i < 8; i++) {
    int row = m0 + (w >> 2) * 64 + (i & 3) * 16 + (i >> 2) * 128 + lg * 4;
#pragma unroll
    for (int j = 0; j < 4; j++) {
      int col = n0 + (w & 3) * 32 + (j & 1) * 16 + (j >> 1) * 128 + lrow;
#pragma unroll
      for (int jj = 0; jj < 4; jj++)
        C[(size_t)(row + jj) * ldc + col] = (CT)acc[i][j][jj];
    }
  }
}

// ---------------------------------------------------------------------------
// 256x128 GEMM, 2 phases/K-tile, ldc-strided output.
// ---------------------------------------------------------------------------
template<typename CT>
__global__ __launch_bounds__(512, 2) void gemm128(const __bf16* __restrict__ A,
                                                  const __bf16* __restrict__ Bt,
                                                  CT* __restrict__ C,
                                                  int K, int ldc, int nbx) {
  __shared__ char lds[98304];
  const int tid = threadIdx.x;
  const int l = tid & 63, w = tid >> 6;
  const int lrow = l & 15, lg = l >> 4;
  const int sw = (lrow & 7) << 4;

  int nwg = gridDim.x;
  int swz = (blockIdx.x & 7) * (nwg >> 3) + (blockIdx.x >> 3);
  int bx = swz % nbx, by = swz / nbx;
  int m0 = by * 256, n0 = bx * 128;

  const int rA = w * 8 + (l >> 3);
  const int csw = ((l & 7) ^ (l >> 3)) * 8;
  const __bf16* As_[2][2];
  const __bf16* Bs_[2];
#pragma unroll
  for (int h = 0; h < 2; h++)
#pragma unroll
    for (int p = 0; p < 2; p++)
      As_[h][p] = A + (size_t)(m0 + h * 128 + p * 64 + rA) * K + csw;
#pragma unroll
  for (int p = 0; p < 2; p++)
    Bs_[p] = Bt + (size_t)(n0 + p * 64 + rA) * K + csw;

  auto stageA = [&](int par, int h, int kt) {
#pragma unroll
    for (int p = 0; p < 2; p++)
      gload16(As_[h][p] + kt * 64,
              (const __bf16*)(lds + par * 32768 + h * 16384 + p * 8192 + w * 1024));
  };
  auto stageB = [&](int par, int kt) {
#pragma unroll
    for (int p = 0; p < 2; p++)
      gload16(Bs_[p] + kt * 64,
              (const __bf16*)(lds + 65536 + par * 16384 + p * 8192 + w * 1024));
  };

  const int arbase = (w >> 2) * 64 + lrow;
  const int brbase = (w & 3) * 32 + lrow;

  bf16x8 aA[4][2];
  bf16x8 bB[2][2];

  auto readA = [&](int par, int ah) {
#pragma unroll
    for (int i = 0; i < 4; i++)
#pragma unroll
      for (int kk = 0; kk < 2; kk++)
        aA[i][kk] = *reinterpret_cast<const bf16x8*>(
            lds + par * 32768 + (arbase + i * 16 + ah * 128) * 128 +
            ((kk * 64 + lg * 16) ^ sw));
  };
  auto readB = [&](int par) {
#pragma unroll
    for (int j = 0; j < 2; j++)
#pragma unroll
      for (int kk = 0; kk < 2; kk++)
        bB[j][kk] = *reinterpret_cast<const bf16x8*>(
            lds + 65536 + par * 16384 + (brbase + j * 16) * 128 +
            ((kk * 64 + lg * 16) ^ sw));
  };

  f32x4 acc[8][2];
#pragma unroll
  for (int i = 0; i < 8; i++)
#pragma unroll
    for (int j = 0; j < 2; j++) {
      acc[i][j][0] = 0.f; acc[i][j][1] = 0.f; acc[i][j][2] = 0.f; acc[i][j][3] = 0.f;
    }

  const int NT = K >> 6;

  stageA(0, 0, 0); stageA(0, 1, 0); stageB(0, 0);
  stageA(1, 0, 1);
  __builtin_amdgcn_sched_barrier(0);
  asm volatile("s_waitcnt vmcnt(2)" ::: "memory");
  SBAR();

  for (int t = 0; t < NT; t++) {
    const int par = t & 1, npar = par ^ 1;
    const int t1 = (t + 1 < NT) ? t + 1 : 0;
    const int t2 = (t + 2 < NT) ? t + 2 : 0;

#define MFMA_HALF(AH)                                                        \
  __builtin_amdgcn_s_setprio(1);                                             \
  _Pragma("unroll") for (int i4 = 0; i4 < 4; i4++)                           \
      _Pragma("unroll") for (int j2 = 0; j2 < 2; j2++)                       \
          _Pragma("unroll") for (int kk = 0; kk < 2; kk++)                   \
              acc[(AH)*4 + i4][j2] =                                         \
                  mfma16(aA[i4][kk], bB[j2][kk], acc[(AH)*4 + i4][j2]);      \
  __builtin_amdgcn_s_setprio(0);

    readA(par, 0);
    readB(par);
    stageA(npar, 1, t1);
    stageB(npar, t1);
    SBAR();
    MFMA_HALF(0);
    SBAR();
    readA(par, 1);
    stageA(par, 0, t2);
    SBAR();
    MFMA_HALF(1);
    __builtin_amdgcn_sched_barrier(0);
    asm volatile("s_waitcnt vmcnt(2)" ::: "memory");
    SBAR();
#undef MFMA_HALF
  }

#pragma unroll
  for (int i = 0; i < 8; i++) {
    int row = m0 + (w >> 2) * 64 + (i & 3) * 16 + (i >> 2) * 128 + lg * 4;
#pragma unroll
    for (int j = 0; j < 2; j++) {
      int col = n0 + (w & 3) * 32 + j * 16 + lrow;
#pragma unroll
      for (int jj = 0; jj < 4; jj++)
        C[(size_t)(row + jj) * ldc + col] = (CT)acc[i][j][jj];
    }
  }
}

// ---------------------------------------------------------------------------
// RoPE, in-place on fused qkv buffer, vectorized.
// ---------------------------------------------------------------------------
__global__ __launch_bounds__(256) void rope_kernel(__bf16* __restrict__ qkv,
                                                   const int* __restrict__ pos) {
  int row = blockIdx.x;
  int t = threadIdx.x;
  float p = (float)pos[row];
  __bf16* rbase = qkv + (size_t)row * QKVW;

  {
    int head = t >> 3, chunk = t & 7;
    __bf16* base = rbase + head * HD + chunk * 8;
    bf16x8 x1 = *reinterpret_cast<const bf16x8*>(base);
    bf16x8 x2 = *reinterpret_cast<const bf16x8*>(base + 64);
    bf16x8 o1, o2;
#pragma unroll
    for (int e = 0; e < 8; e++) {
      float ang = p * exp2f(-0.20762050f * (float)(chunk * 8 + e));
      float s, c;
      __sincosf(ang, &s, &c);
      float a = (float)x1[e], b2 = (float)x2[e];
      o1[e] = (__bf16)(a * c - b2 * s);
      o2[e] = (__bf16)(b2 * c + a * s);
    }
    *reinterpret_cast<bf16x8*>(base) = o1;
    *reinterpret_cast<bf16x8*>(base + 64) = o2;
  }
  if (t < 64) {
    int head = t >> 3, chunk = t & 7;
    __bf16* base = rbase + 4096 + head * HD + chunk * 8;
    bf16x8 x1 = *reinterpret_cast<const bf16x8*>(base);
    bf16x8 x2 = *reinterpret_cast<const bf16x8*>(base + 64);
    bf16x8 o1, o2;
#pragma unroll
    for (int e = 0; e < 8; e++) {
      float ang = p * exp2f(-0.20762050f * (float)(chunk * 8 + e));
      float s, c;
      __sincosf(ang, &s, &c);
      float a = (float)x1[e], b2 = (float)x2[e];
      o1[e] = (__bf16)(a * c - b2 * s);
      o2[e] = (__bf16)(b2 * c + a * s);
    }
    *reinterpret_cast<bf16x8*>(base) = o1;
    *reinterpret_cast<bf16x8*>(base + 64) = o2;
  }
}

// ---------------------------------------------------------------------------
// Flash attention, causal, GQA. 256 blocks; each block processes TWO q-blocks
// (qblk 7-p then qblk p) sequentially -> uniform 36 kv-tiles/block.
// T13 PROPER fast-path: per-lane growth check (lane_max > m + 8) -> __any;
// fast path (common) skips the 32 shfl row-reduce AND the rescale entirely
// (P bounded by 2^8, ssum/ov in f32 -> exact-safe). Slow path = full reduce.
// ---------------------------------------------------------------------------
__global__ __launch_bounds__(512) void attn_kernel(const __bf16* __restrict__ qkv,
                                                   const __bf16* __restrict__ vt,
                                                   __bf16* __restrict__ out) {
  __shared__ __bf16 Ks[64 * 128];      // [kv][d], swizzled, 16 KB
  __shared__ __bf16 Vs[128 * 64];      // [d][kv], swizzled, 16 KB
  __shared__ __bf16 Ps[8][32][68];     // per-wave P, padded, 34 KB

  int tid = threadIdx.x;
  int l = tid & 63, w = tid >> 6;
  int bid = blockIdx.x;                // 0..255
  int pairIdx = bid >> 6;              // 0..3
  int rem = bid & 63;
  int h = rem & 31, b = rem >> 5;
  int kvh = h >> 2;
  int lrow = l & 15, lg = l >> 4;
  int sw = (lrow & 7) << 4;
  const float SCL = 0.08838834764831845f * 1.4426950408889634f;  // 1/sqrt(128)*log2e

  const __bf16* kbase = qkv + (size_t)(b * S_LEN) * QKVW + 4096 + kvh * HD;
  const __bf16* vbase = vt + ((size_t)(b * NKV + kvh) * HD) * S_LEN;

  int krow = tid >> 3;
  int kslot = (tid & 7) * 2;
  int vrow = tid >> 2;
  int vslot = (tid & 3) * 2;
  char* KsB = (char*)Ks;
  char* VsB = (char*)Vs;
  int koff0 = krow * 256 + ((kslot * 16) ^ ((krow & 7) << 4));
  int koff1 = krow * 256 + (((kslot + 1) * 16) ^ ((krow & 7) << 4));
  int voff0 = vrow * 128 + ((vslot * 16) ^ ((vrow & 7) << 4));
  int voff1 = vrow * 128 + (((vslot + 1) * 16) ^ ((vrow & 7) << 4));
  const __bf16* kg = kbase + (size_t)krow * QKVW + kslot * 8;
  const __bf16* vg = vbase + (size_t)vrow * S_LEN + vslot * 8;

#pragma unroll 1
  for (int pass = 0; pass < 2; pass++) {
    int qblk = pass == 0 ? (7 - pairIdx) : pairIdx;
    int q0w = qblk * 256 + w * 32;

    // Q fragments, pre-scaled
    bf16x8 qf[2][4];
#pragma unroll
    for (int mi = 0; mi < 2; mi++) {
      const __bf16* qp = qkv + (size_t)(b * S_LEN + q0w + mi * 16 + lrow) * QKVW + h * HD + lg * 8;
#pragma unroll
      for (int kk = 0; kk < 4; kk++) {
        bf16x8 t = *reinterpret_cast<const bf16x8*>(qp + kk * 32);
#pragma unroll
        for (int e = 0; e < 8; e++) t[e] = (__bf16)((float)t[e] * SCL);
        qf[mi][kk] = t;
      }
    }

    f32x4 ov[2][8];
#pragma unroll
    for (int mi = 0; mi < 2; mi++)
#pragma unroll
      for (int n = 0; n < 8; n++) {
        ov[mi][n][0] = 0.f; ov[mi][n][1] = 0.f; ov[mi][n][2] = 0.f; ov[mi][n][3] = 0.f;
      }
    float m[2][4], ssum[2][4];
#pragma unroll
    for (int mi = 0; mi < 2; mi++)
#pragma unroll
      for (int jj = 0; jj < 4; jj++) { m[mi][jj] = -3.0e38f; ssum[mi][jj] = 0.f; }

    int nt = 4 * qblk + 4;
    bf16x8 kr0, kr1, vr0, vr1;

    if (pass) __syncthreads();   // previous pass done reading LDS
    kr0 = *reinterpret_cast<const bf16x8*>(kg);
    kr1 = *reinterpret_cast<const bf16x8*>(kg + 8);
    vr0 = *reinterpret_cast<const bf16x8*>(vg);
    vr1 = *reinterpret_cast<const bf16x8*>(vg + 8);
    *reinterpret_cast<bf16x8*>(KsB + koff0) = kr0;
    *reinterpret_cast<bf16x8*>(KsB + koff1) = kr1;
    *reinterpret_cast<bf16x8*>(VsB + voff0) = vr0;
    *reinterpret_cast<bf16x8*>(VsB + voff1) = vr1;
    __syncthreads();

    for (int t = 0;; t++) {
      int kv0 = t * 64;
      bool more = (t + 1 < nt);
      if (more) {
        int kvn = kv0 + 64;
        kr0 = *reinterpret_cast<const bf16x8*>(kg + (size_t)kvn * QKVW);
        kr1 = *reinterpret_cast<const bf16x8*>(kg + (size_t)kvn * QKVW + 8);
        vr0 = *reinterpret_cast<const bf16x8*>(vg + kvn);
        vr1 = *reinterpret_cast<const bf16x8*>(vg + kvn + 8);
      }

      bool active = (kv0 <= q0w + 31);
      if (active) {
        f32x4 sc[2][4];
#pragma unroll
        for (int mi = 0; mi < 2; mi++)
#pragma unroll
          for (int c = 0; c < 4; c++) {
            sc[mi][c][0] = 0.f; sc[mi][c][1] = 0.f; sc[mi][c][2] = 0.f; sc[mi][c][3] = 0.f;
          }
#pragma unroll
        for (int c = 0; c < 4; c++) {
          int rb = (c * 16 + lrow) * 256;
#pragma unroll
          for (int kk = 0; kk < 4; kk++) {
            bf16x8 kf = *reinterpret_cast<const bf16x8*>(KsB + rb + ((kk * 64 + lg * 16) ^ sw));
            sc[0][c] = mfma16(qf[0][kk], kf, sc[0][c]);
            sc[1][c] = mfma16(qf[1][kk], kf, sc[1][c]);
          }
        }

        // causal mask
        bool bound = (kv0 + 64 > q0w);
        if (bound) {
#pragma unroll
          for (int mi = 0; mi < 2; mi++)
#pragma unroll
            for (int jj = 0; jj < 4; jj++) {
              int qidx = q0w + mi * 16 + lg * 4 + jj;
              if (kv0 + lrow > qidx)      sc[mi][0][jj] = -3.0e38f;
              if (kv0 + 16 + lrow > qidx) sc[mi][1][jj] = -3.0e38f;
              if (kv0 + 32 + lrow > qidx) sc[mi][2][jj] = -3.0e38f;
              if (kv0 + 48 + lrow > qidx) sc[mi][3][jj] = -3.0e38f;
            }
        }

        // T13 cheap growth check: per-lane max vs m + 8
        bool lanegrow = false;
#pragma unroll
        for (int mi = 0; mi < 2; mi++)
#pragma unroll
          for (int jj = 0; jj < 4; jj++) {
            float lm = fmaxf(fmaxf(sc[mi][0][jj], sc[mi][1][jj]),
                             fmaxf(sc[mi][2][jj], sc[mi][3][jj]));
            lanegrow |= (lm > m[mi][jj] + 8.0f);
          }

        if (!__any(lanegrow)) {
          // ---- FAST PATH: m unchanged, no shfl, no rescale. P <= 2^8.
#pragma unroll
          for (int mi = 0; mi < 2; mi++)
#pragma unroll
            for (int jj = 0; jj < 4; jj++) {
              float mn = m[mi][jj];
              float p0 = exp2f(sc[mi][0][jj] - mn), p1 = exp2f(sc[mi][1][jj] - mn);
              float p2 = exp2f(sc[mi][2][jj] - mn), p3 = exp2f(sc[mi][3][jj] - mn);
              ssum[mi][jj] += (p0 + p1) + (p2 + p3);
              int pr = mi * 16 + lg * 4 + jj;
              Ps[w][pr][lrow]      = (__bf16)p0;
              Ps[w][pr][16 + lrow] = (__bf16)p1;
              Ps[w][pr][32 + lrow] = (__bf16)p2;
              Ps[w][pr][48 + lrow] = (__bf16)p3;
            }
        } else {
          // ---- SLOW PATH: full row-max reduce, rescale, update m.
          float es[2][4];
          bool anyr = false;
#pragma unroll
          for (int mi = 0; mi < 2; mi++)
#pragma unroll
            for (int jj = 0; jj < 4; jj++) {
              float r = fmaxf(fmaxf(sc[mi][0][jj], sc[mi][1][jj]),
                              fmaxf(sc[mi][2][jj], sc[mi][3][jj]));
              r = fmaxf(r, __shfl_xor(r, 1));
              r = fmaxf(r, __shfl_xor(r, 2));
              r = fmaxf(r, __shfl_xor(r, 4));
              r = fmaxf(r, __shfl_xor(r, 8));
              float mo = m[mi][jj];
              bool grow = (r > mo + 8.0f);
              float mn = grow ? r : mo;
              float e = grow ? exp2f(mo - r) : 1.0f;
              es[mi][jj] = e;
              anyr |= grow;
              m[mi][jj] = mn;
              float p0 = exp2f(sc[mi][0][jj] - mn), p1 = exp2f(sc[mi][1][jj] - mn);
              float p2 = exp2f(sc[mi][2][jj] - mn), p3 = exp2f(sc[mi][3][jj] - mn);
              ssum[mi][jj] = ssum[mi][jj] * e + ((p0 + p1) + (p2 + p3));
              int pr = mi * 16 + lg * 4 + jj;
              Ps[w][pr][lrow]      = (__bf16)p0;
              Ps[w][pr][16 + lrow] = (__bf16)p1;
              Ps[w][pr][32 + lrow] = (__bf16)p2;
              Ps[w][pr][48 + lrow] = (__bf16)p3;
            }
          if (__any(anyr)) {
#pragma unroll
            for (int mi = 0; mi < 2; mi++)
#pragma unroll
              for (int n = 0; n < 8; n++)
#pragma unroll
                for (int jj = 0; jj < 4; jj++) ov[mi][n][jj] *= es[mi][jj];
          }
        }

#pragma unroll
        for (int kvs = 0; kvs < 2; kvs++) {
          bf16x8 pf0 = *reinterpret_cast<const bf16x8*>(&Ps[w][lrow][kvs * 32 + lg * 8]);
          bf16x8 pf1 = *reinterpret_cast<const bf16x8*>(&Ps[w][16 + lrow][kvs * 32 + lg * 8]);
#pragma unroll
          for (int n = 0; n < 8; n++) {
            bf16x8 vf = *reinterpret_cast<const bf16x8*>(
                VsB + (n * 16 + lrow) * 128 + ((kvs * 64 + lg * 16) ^ sw));
            ov[0][n] = mfma16(pf0, vf, ov[0][n]);
            ov[1][n] = mfma16(pf1, vf, ov[1][n]);
          }
        }
      }

      if (!more) break;
      __syncthreads();
      *reinterpret_cast<bf16x8*>(KsB + koff0) = kr0;
      *reinterpret_cast<bf16x8*>(KsB + koff1) = kr1;
      *reinterpret_cast<bf16x8*>(VsB + voff0) = vr0;
      *reinterpret_cast<bf16x8*>(VsB + voff1) = vr1;
      __syncthreads();
    }

    float rinv[2][4];
#pragma unroll
    for (int mi = 0; mi < 2; mi++)
#pragma unroll
      for (int jj = 0; jj < 4; jj++) {
        float s = ssum[mi][jj];
        s += __shfl_xor(s, 1);
        s += __shfl_xor(s, 2);
        s += __shfl_xor(s, 4);
        s += __shfl_xor(s, 8);
        rinv[mi][jj] = 1.0f / s;
      }
#pragma unroll
    for (int mi = 0; mi < 2; mi++)
#pragma unroll
      for (int n = 0; n < 8; n++)
#pragma unroll
        for (int jj = 0; jj < 4; jj++) {
          out[(size_t)(b * S_LEN + q0w + mi * 16 + lg * 4 + jj) * HIDDEN + h * HD + n * 16 + lrow] =
              (__bf16)(ov[mi][n][jj] * rinv[mi][jj]);
        }
  }
}

// ---------------------------------------------------------------------------
// Workspace layout (bytes), total 142606336:
//   h_bf / a_buf (aliased) @ 0          33554432   bf16 [4096][4096]
//   Wt (qkv^T, later Wo^T) @ 33554432   50331648   bf16 [6144][4096]
//   qkv_buf                @ 83886080   50331648   bf16 [4096][6144]
//   vt_buf                 @ 134217728   8388608   bf16 [16][128][2048]
// ---------------------------------------------------------------------------
extern "C" void kernel_launch(void* const* d_in, const int* in_sizes, int n_in,
                              void* d_out, int out_size, void* d_ws, size_t ws_size,
                              hipStream_t stream) {
  const float* hidden = (const float*)d_in[0];
  const int* posids   = (const int*)d_in[1];
  const float* Wq     = (const float*)d_in[2];
  const float* Wk     = (const float*)d_in[3];
  const float* Wv     = (const float*)d_in[4];
  const float* Wo     = (const float*)d_in[5];
  float* out = (float*)d_out;

  char* ws = (char*)d_ws;
  __bf16* h_bf    = (__bf16*)(ws + 0);
  __bf16* a_buf   = h_bf;  // aliased: h last read by QKV GEMMs, before attn writes
  __bf16* Wt      = (__bf16*)(ws + 33554432);
  __bf16* qkv_buf = (__bf16*)(ws + 83886080);
  __bf16* vt_buf  = (__bf16*)(ws + 134217728);

  dim3 b256(256), b328(32, 8), b512(512);

  // 1. hidden -> bf16
  cvt_kernel<<<dim3(MROWS * HIDDEN / (256 * 8)), b256, 0, stream>>>(hidden, h_bf, MROWS * HIDDEN);

  // 2. fused weight transpose: Wt = [Wq^T ; Wk^T ; Wv^T]  [6144][4096]
  tcvt3_kernel<<<dim3(128, 128, 3), b328, 0, stream>>>(Wq, Wk, Wv, Wt);

  // 3a. QKV main: cols [0,4096) via 256^2 tiles -> 256 blocks (1 round)
  gemm256<__bf16><<<dim3(256), b512, 0, stream>>>(
      h_bf, Wt, qkv_buf, HIDDEN, QKVW, 4096 / 256);
  // 3b. QKV tail: cols [4096,6144) via 256x128 tiles -> 256 blocks
  gemm128<__bf16><<<dim3(256), b512, 0, stream>>>(
      h_bf, Wt + (size_t)4096 * 4096, qkv_buf + 4096, HIDDEN, QKVW, 2048 / 128);

  // 4. RoPE on q,k (in fused buffer), vectorized
  rope_kernel<<<dim3(MROWS), b256, 0, stream>>>(qkv_buf, posids);

  // 5. V^T
  tvt_kernel<<<dim3(HD / 32, S_LEN / 32, BATCH * NKV), b328, 0, stream>>>(qkv_buf, vt_buf);

  // 6. attention -> a_buf  (256 blocks, each exactly 36 kv-tiles)
  attn_kernel<<<dim3(4 * NH * BATCH), b512, 0, stream>>>(qkv_buf, vt_buf, a_buf);

  // 7. Wo^T (reuse Wt)
  tcvt_f32<<<dim3(HIDDEN / 32, HIDDEN / 32), b328, 0, stream>>>(Wo, Wt, HIDDEN, HIDDEN);

  // 8. out = a @ Wo  (fp32 out; 256 blocks = 1 balanced round)
  gemm256<float><<<dim3(256), b512, 0, stream>>>(
      a_buf, Wt, out, HIDDEN, HIDDEN, HIDDEN / 256);
}

// Round 9
// 532.936 us; speedup vs baseline: 1.1507x; 1.1507x over previous
//
#include <hip/hip_runtime.h>
#include <hip/hip_bf16.h>
#include <math.h>

#define HIDDEN 4096
#define NH 32
#define NKV 8
#define HD 128
#define S_LEN 2048
#define BATCH 2
#define MROWS (BATCH * S_LEN)  // 4096
#define QKVW 6144              // fused q|k|v row width

typedef __attribute__((ext_vector_type(8))) __bf16 bf16x8;
typedef __attribute__((ext_vector_type(4))) float f32x4;

__device__ __forceinline__ f32x4 mfma16(bf16x8 a, bf16x8 b, f32x4 c) {
  return __builtin_amdgcn_mfma_f32_16x16x32_bf16(a, b, c, 0, 0, 0);
}

// async global->LDS, 16B/lane; LDS dest = wave-uniform base, HW adds lane*16.
__device__ __forceinline__ void gload16(const __bf16* g, const __bf16* l) {
  __builtin_amdgcn_global_load_lds(
      (const __attribute__((address_space(1))) void*)g,
      (__attribute__((address_space(3))) void*)l, 16, 0, 0);
}

#define SBAR()                          \
  do {                                  \
    __builtin_amdgcn_sched_barrier(0);  \
    __builtin_amdgcn_s_barrier();       \
    __builtin_amdgcn_sched_barrier(0);  \
  } while (0)

// ---------------------------------------------------------------------------
// fp32 -> bf16 elementwise convert (vectorized)
// ---------------------------------------------------------------------------
__global__ __launch_bounds__(256) void cvt_kernel(const float* __restrict__ in,
                                                  __bf16* __restrict__ out, int n) {
  int i = (blockIdx.x * 256 + threadIdx.x) * 8;
  if (i >= n) return;
  float4 a = *reinterpret_cast<const float4*>(in + i);
  float4 b = *reinterpret_cast<const float4*>(in + i + 4);
  bf16x8 t;
  t[0] = (__bf16)a.x; t[1] = (__bf16)a.y; t[2] = (__bf16)a.z; t[3] = (__bf16)a.w;
  t[4] = (__bf16)b.x; t[5] = (__bf16)b.y; t[6] = (__bf16)b.z; t[7] = (__bf16)b.w;
  *reinterpret_cast<bf16x8*>(out + i) = t;
}

// ---------------------------------------------------------------------------
// Fused weight transpose+convert: z=0 Wq (4096 cols), z=1 Wk, z=2 Wv (1024).
// ---------------------------------------------------------------------------
__global__ __launch_bounds__(256) void tcvt3_kernel(const float* __restrict__ Wq,
                                                    const float* __restrict__ Wk,
                                                    const float* __restrict__ Wv,
                                                    __bf16* __restrict__ Wt) {
  __shared__ float t[32][33];
  int z = blockIdx.z;
  const float* in;
  __bf16* out;
  int C;
  if (z == 0)      { in = Wq; out = Wt;                         C = 4096; }
  else if (z == 1) { in = Wk; out = Wt + (size_t)4096 * 4096;   C = 1024; }
  else             { in = Wv; out = Wt + (size_t)5120 * 4096;   C = 1024; }
  if ((int)blockIdx.x * 32 >= C) return;
  int tx = threadIdx.x, ty = threadIdx.y;
  int r0 = blockIdx.y * 32, c0 = blockIdx.x * 32;
#pragma unroll
  for (int i = 0; i < 4; i++)
    t[ty + i * 8][tx] = in[(size_t)(r0 + ty + i * 8) * C + c0 + tx];
  __syncthreads();
#pragma unroll
  for (int i = 0; i < 4; i++)
    out[(size_t)(c0 + ty + i * 8) * 4096 + r0 + tx] = (__bf16)t[tx][ty + i * 8];
}

// single transpose for Wo
__global__ __launch_bounds__(256) void tcvt_f32(const float* __restrict__ in,
                                                __bf16* __restrict__ out,
                                                int R, int C) {
  __shared__ float t[32][33];
  int tx = threadIdx.x, ty = threadIdx.y;
  int r0 = blockIdx.y * 32, c0 = blockIdx.x * 32;
#pragma unroll
  for (int i = 0; i < 4; i++)
    t[ty + i * 8][tx] = in[(size_t)(r0 + ty + i * 8) * C + c0 + tx];
  __syncthreads();
#pragma unroll
  for (int i = 0; i < 4; i++)
    out[(size_t)(c0 + ty + i * 8) * R + r0 + tx] = (__bf16)t[tx][ty + i * 8];
}

// ---------------------------------------------------------------------------
// V transpose: qkv [B*S][QKVW] (v at col 5120 + kvh*HD) -> vt [B*NKV][HD][S].
// ---------------------------------------------------------------------------
__global__ __launch_bounds__(256) void tvt_kernel(const __bf16* __restrict__ qkv,
                                                  __bf16* __restrict__ vt) {
  __shared__ __bf16 t[32][33];
  int tx = threadIdx.x, ty = threadIdx.y;
  int z = blockIdx.z;
  int b = z >> 3, kvh = z & 7;
  int kv0 = blockIdx.y * 32, d0 = blockIdx.x * 32;
#pragma unroll
  for (int i = 0; i < 4; i++)
    t[ty + i * 8][tx] =
        qkv[(size_t)(b * S_LEN + kv0 + ty + i * 8) * QKVW + 5120 + kvh * HD + d0 + tx];
  __syncthreads();
#pragma unroll
  for (int i = 0; i < 4; i++)
    vt[((size_t)z * HD + d0 + ty + i * 8) * S_LEN + kv0 + tx] = t[tx][ty + i * 8];
}

// ---------------------------------------------------------------------------
// 256x256 8-phase GEMM (m201-style): C[M,N] = A * Bt^T, ldc-strided output.
// ---------------------------------------------------------------------------
template<typename CT>
__global__ __launch_bounds__(512, 2) void gemm256(const __bf16* __restrict__ A,
                                                  const __bf16* __restrict__ Bt,
                                                  CT* __restrict__ C,
                                                  int K, int ldc, int nbx) {
  __shared__ char lds[131072];
  const int tid = threadIdx.x;
  const int l = tid & 63, w = tid >> 6;
  const int lrow = l & 15, lg = l >> 4;
  const int sw = (lrow & 7) << 4;

  int nwg = gridDim.x;
  int swz = (blockIdx.x & 7) * (nwg >> 3) + (blockIdx.x >> 3);
  int bx = swz % nbx, by = swz / nbx;
  int m0 = by * 256, n0 = bx * 256;

  const int rA = w * 8 + (l >> 3);
  const int csw = ((l & 7) ^ (l >> 3)) * 8;  // inverse-swizzled source col
  const __bf16* As_[2][2];
  const __bf16* Bs_[2][2];
#pragma unroll
  for (int h = 0; h < 2; h++)
#pragma unroll
    for (int p = 0; p < 2; p++) {
      As_[h][p] = A + (size_t)(m0 + h * 128 + p * 64 + rA) * K + csw;
      Bs_[h][p] = Bt + (size_t)(n0 + h * 128 + p * 64 + rA) * K + csw;
    }

  auto stageA = [&](int par, int h, int kt) {
#pragma unroll
    for (int p = 0; p < 2; p++)
      gload16(As_[h][p] + kt * 64,
              (const __bf16*)(lds + par * 32768 + h * 16384 + p * 8192 + w * 1024));
  };
  auto stageB = [&](int par, int h, int kt) {
#pragma unroll
    for (int p = 0; p < 2; p++)
      gload16(Bs_[h][p] + kt * 64,
              (const __bf16*)(lds + 65536 + par * 32768 + h * 16384 + p * 8192 + w * 1024));
  };

  const int arbase = (w >> 2) * 64 + lrow;
  const int brbase = (w & 3) * 32 + lrow;

  bf16x8 aA[4][2];
  bf16x8 bB[2][2][2];

  auto readA = [&](int par, int ah) {
#pragma unroll
    for (int i = 0; i < 4; i++)
#pragma unroll
      for (int kk = 0; kk < 2; kk++)
        aA[i][kk] = *reinterpret_cast<const bf16x8*>(
            lds + par * 32768 + (arbase + i * 16 + ah * 128) * 128 +
            ((kk * 64 + lg * 16) ^ sw));
  };
  auto readB = [&](int par, int bh) {
#pragma unroll
    for (int j = 0; j < 2; j++)
#pragma unroll
      for (int kk = 0; kk < 2; kk++)
        bB[bh][j][kk] = *reinterpret_cast<const bf16x8*>(
            lds + 65536 + par * 32768 + (brbase + j * 16 + bh * 128) * 128 +
            ((kk * 64 + lg * 16) ^ sw));
  };

  f32x4 acc[8][4];
#pragma unroll
  for (int i = 0; i < 8; i++)
#pragma unroll
    for (int j = 0; j < 4; j++) {
      acc[i][j][0] = 0.f; acc[i][j][1] = 0.f; acc[i][j][2] = 0.f; acc[i][j][3] = 0.f;
    }

  const int NT = K >> 6;

  stageA(0, 0, 0); stageA(0, 1, 0); stageB(0, 0, 0); stageB(0, 1, 0);
  stageA(1, 0, 1); stageB(1, 0, 1);
  __builtin_amdgcn_sched_barrier(0);
  asm volatile("s_waitcnt vmcnt(4)" ::: "memory");
  SBAR();

  for (int t = 0; t < NT; t++) {
    const int par = t & 1, npar = par ^ 1;
    const int t1 = (t + 1 < NT) ? t + 1 : 0;
    const int t2 = (t + 2 < NT) ? t + 2 : 0;

#define MFMA_QUAD(AH, BH)                                                   \
  __builtin_amdgcn_s_setprio(1);                                            \
  _Pragma("unroll") for (int i4 = 0; i4 < 4; i4++)                          \
      _Pragma("unroll") for (int j2 = 0; j2 < 2; j2++)                      \
          _Pragma("unroll") for (int kk = 0; kk < 2; kk++)                  \
              acc[(AH)*4 + i4][(BH)*2 + j2] =                               \
                  mfma16(aA[i4][kk], bB[BH][j2][kk], acc[(AH)*4 + i4][(BH)*2 + j2]); \
  __builtin_amdgcn_s_setprio(0);

    readA(par, 0);
    readB(par, 0);
    stageA(npar, 1, t1);
    SBAR();
    MFMA_QUAD(0, 0);
    SBAR();
    readB(par, 1);
    stageB(npar, 1, t1);
    SBAR();
    MFMA_QUAD(0, 1);
    SBAR();
    readA(par, 1);
    stageA(par, 0, t2);
    SBAR();
    MFMA_QUAD(1, 0);
    SBAR();
    stageB(par, 0, t2);
    SBAR();
    MFMA_QUAD(1, 1);
    __builtin_amdgcn_sched_barrier(0);
    asm volatile("s_waitcnt vmcnt(4)" ::: "memory");
    SBAR();
#undef MFMA_QUAD
  }

#pragma unroll
  for (int i = 0; i < 8; i++) {
    int row = m0 + (w >> 2) * 64 + (i & 3) * 16 + (i >> 2) * 128 + lg * 4;
#pragma unroll
    for (int j = 0; j < 4; j++) {
      int col = n0 + (w & 3) * 32 + (j & 1) * 16 + (j >> 1) * 128 + lrow;
#pragma unroll
      for (int jj = 0; jj < 4; jj++)
        C[(size_t)(row + jj) * ldc + col] = (CT)acc[i][j][jj];
    }
  }
}

// ---------------------------------------------------------------------------
// 256x128 GEMM, 2 phases/K-tile, ldc-strided output.
// ---------------------------------------------------------------------------
template<typename CT>
__global__ __launch_bounds__(512, 2) void gemm128(const __bf16* __restrict__ A,
                                                  const __bf16* __restrict__ Bt,
                                                  CT* __restrict__ C,
                                                  int K, int ldc, int nbx) {
  __shared__ char lds[98304];
  const int tid = threadIdx.x;
  const int l = tid & 63, w = tid >> 6;
  const int lrow = l & 15, lg = l >> 4;
  const int sw = (lrow & 7) << 4;

  int nwg = gridDim.x;
  int swz = (blockIdx.x & 7) * (nwg >> 3) + (blockIdx.x >> 3);
  int bx = swz % nbx, by = swz / nbx;
  int m0 = by * 256, n0 = bx * 128;

  const int rA = w * 8 + (l >> 3);
  const int csw = ((l & 7) ^ (l >> 3)) * 8;
  const __bf16* As_[2][2];
  const __bf16* Bs_[2];
#pragma unroll
  for (int h = 0; h < 2; h++)
#pragma unroll
    for (int p = 0; p < 2; p++)
      As_[h][p] = A + (size_t)(m0 + h * 128 + p * 64 + rA) * K + csw;
#pragma unroll
  for (int p = 0; p < 2; p++)
    Bs_[p] = Bt + (size_t)(n0 + p * 64 + rA) * K + csw;

  auto stageA = [&](int par, int h, int kt) {
#pragma unroll
    for (int p = 0; p < 2; p++)
      gload16(As_[h][p] + kt * 64,
              (const __bf16*)(lds + par * 32768 + h * 16384 + p * 8192 + w * 1024));
  };
  auto stageB = [&](int par, int kt) {
#pragma unroll
    for (int p = 0; p < 2; p++)
      gload16(Bs_[p] + kt * 64,
              (const __bf16*)(lds + 65536 + par * 16384 + p * 8192 + w * 1024));
  };

  const int arbase = (w >> 2) * 64 + lrow;
  const int brbase = (w & 3) * 32 + lrow;

  bf16x8 aA[4][2];
  bf16x8 bB[2][2];

  auto readA = [&](int par, int ah) {
#pragma unroll
    for (int i = 0; i < 4; i++)
#pragma unroll
      for (int kk = 0; kk < 2; kk++)
        aA[i][kk] = *reinterpret_cast<const bf16x8*>(
            lds + par * 32768 + (arbase + i * 16 + ah * 128) * 128 +
            ((kk * 64 + lg * 16) ^ sw));
  };
  auto readB = [&](int par) {
#pragma unroll
    for (int j = 0; j < 2; j++)
#pragma unroll
      for (int kk = 0; kk < 2; kk++)
        bB[j][kk] = *reinterpret_cast<const bf16x8*>(
            lds + 65536 + par * 16384 + (brbase + j * 16) * 128 +
            ((kk * 64 + lg * 16) ^ sw));
  };

  f32x4 acc[8][2];
#pragma unroll
  for (int i = 0; i < 8; i++)
#pragma unroll
    for (int j = 0; j < 2; j++) {
      acc[i][j][0] = 0.f; acc[i][j][1] = 0.f; acc[i][j][2] = 0.f; acc[i][j][3] = 0.f;
    }

  const int NT = K >> 6;

  stageA(0, 0, 0); stageA(0, 1, 0); stageB(0, 0);
  stageA(1, 0, 1);
  __builtin_amdgcn_sched_barrier(0);
  asm volatile("s_waitcnt vmcnt(2)" ::: "memory");
  SBAR();

  for (int t = 0; t < NT; t++) {
    const int par = t & 1, npar = par ^ 1;
    const int t1 = (t + 1 < NT) ? t + 1 : 0;
    const int t2 = (t + 2 < NT) ? t + 2 : 0;

#define MFMA_HALF(AH)                                                        \
  __builtin_amdgcn_s_setprio(1);                                             \
  _Pragma("unroll") for (int i4 = 0; i4 < 4; i4++)                           \
      _Pragma("unroll") for (int j2 = 0; j2 < 2; j2++)                       \
          _Pragma("unroll") for (int kk = 0; kk < 2; kk++)                   \
              acc[(AH)*4 + i4][j2] =                                         \
                  mfma16(aA[i4][kk], bB[j2][kk], acc[(AH)*4 + i4][j2]);      \
  __builtin_amdgcn_s_setprio(0);

    readA(par, 0);
    readB(par);
    stageA(npar, 1, t1);
    stageB(npar, t1);
    SBAR();
    MFMA_HALF(0);
    SBAR();
    readA(par, 1);
    stageA(par, 0, t2);
    SBAR();
    MFMA_HALF(1);
    __builtin_amdgcn_sched_barrier(0);
    asm volatile("s_waitcnt vmcnt(2)" ::: "memory");
    SBAR();
#undef MFMA_HALF
  }

#pragma unroll
  for (int i = 0; i < 8; i++) {
    int row = m0 + (w >> 2) * 64 + (i & 3) * 16 + (i >> 2) * 128 + lg * 4;
#pragma unroll
    for (int j = 0; j < 2; j++) {
      int col = n0 + (w & 3) * 32 + j * 16 + lrow;
#pragma unroll
      for (int jj = 0; jj < 4; jj++)
        C[(size_t)(row + jj) * ldc + col] = (CT)acc[i][j][jj];
    }
  }
}

// ---------------------------------------------------------------------------
// RoPE, in-place on fused qkv buffer, vectorized.
// ---------------------------------------------------------------------------
__global__ __launch_bounds__(256) void rope_kernel(__bf16* __restrict__ qkv,
                                                   const int* __restrict__ pos) {
  int row = blockIdx.x;
  int t = threadIdx.x;
  float p = (float)pos[row];
  __bf16* rbase = qkv + (size_t)row * QKVW;

  {
    int head = t >> 3, chunk = t & 7;
    __bf16* base = rbase + head * HD + chunk * 8;
    bf16x8 x1 = *reinterpret_cast<const bf16x8*>(base);
    bf16x8 x2 = *reinterpret_cast<const bf16x8*>(base + 64);
    bf16x8 o1, o2;
#pragma unroll
    for (int e = 0; e < 8; e++) {
      float ang = p * exp2f(-0.20762050f * (float)(chunk * 8 + e));
      float s, c;
      __sincosf(ang, &s, &c);
      float a = (float)x1[e], b2 = (float)x2[e];
      o1[e] = (__bf16)(a * c - b2 * s);
      o2[e] = (__bf16)(b2 * c + a * s);
    }
    *reinterpret_cast<bf16x8*>(base) = o1;
    *reinterpret_cast<bf16x8*>(base + 64) = o2;
  }
  if (t < 64) {
    int head = t >> 3, chunk = t & 7;
    __bf16* base = rbase + 4096 + head * HD + chunk * 8;
    bf16x8 x1 = *reinterpret_cast<const bf16x8*>(base);
    bf16x8 x2 = *reinterpret_cast<const bf16x8*>(base + 64);
    bf16x8 o1, o2;
#pragma unroll
    for (int e = 0; e < 8; e++) {
      float ang = p * exp2f(-0.20762050f * (float)(chunk * 8 + e));
      float s, c;
      __sincosf(ang, &s, &c);
      float a = (float)x1[e], b2 = (float)x2[e];
      o1[e] = (__bf16)(a * c - b2 * s);
      o2[e] = (__bf16)(b2 * c + a * s);
    }
    *reinterpret_cast<bf16x8*>(base) = o1;
    *reinterpret_cast<bf16x8*>(base + 64) = o2;
  }
}

// ---------------------------------------------------------------------------
// Flash attention, causal, GQA. R5-proven structure: 512 blocks (2/CU
// co-resident — cross-block MFMA/VALU overlap), heavy q-blocks dispatched
// first (qblk = 7 - bid>>6), 8 waves x 32 q-rows, KVBLK=64, K/V^T reg-staged
// to XOR-swizzled LDS, T14 async-stage split. SINGLE-path online softmax
// (no branch duplication -> no scratch spills; R8 lesson) with threshold-
// deferred rescale (grow only when row-max rises >8 exp2 units; P <= 2^8,
// ssum/ov f32 -> exact-safe).
// ---------------------------------------------------------------------------
__global__ __launch_bounds__(512) void attn_kernel(const __bf16* __restrict__ qkv,
                                                   const __bf16* __restrict__ vt,
                                                   __bf16* __restrict__ out) {
  __shared__ __bf16 Ks[64 * 128];      // [kv][d], swizzled, 16 KB
  __shared__ __bf16 Vs[128 * 64];      // [d][kv], swizzled, 16 KB
  __shared__ __bf16 Ps[8][32][68];     // per-wave P, padded, 34 KB

  int tid = threadIdx.x;
  int l = tid & 63, w = tid >> 6;
  int bid = blockIdx.x;
  int qblk = 7 - (bid >> 6);           // heavy blocks first
  int rem = bid & 63;
  int h = rem & 31, b = rem >> 5;
  int kvh = h >> 2;
  int q0w = qblk * 256 + w * 32;
  int lrow = l & 15, lg = l >> 4;
  int sw = (lrow & 7) << 4;
  const float SCL = 0.08838834764831845f * 1.4426950408889634f;  // 1/sqrt(128)*log2e

  const __bf16* kbase = qkv + (size_t)(b * S_LEN) * QKVW + 4096 + kvh * HD;
  const __bf16* vbase = vt + ((size_t)(b * NKV + kvh) * HD) * S_LEN;

  int krow = tid >> 3;
  int kslot = (tid & 7) * 2;
  int vrow = tid >> 2;
  int vslot = (tid & 3) * 2;
  char* KsB = (char*)Ks;
  char* VsB = (char*)Vs;
  int koff0 = krow * 256 + ((kslot * 16) ^ ((krow & 7) << 4));
  int koff1 = krow * 256 + (((kslot + 1) * 16) ^ ((krow & 7) << 4));
  int voff0 = vrow * 128 + ((vslot * 16) ^ ((vrow & 7) << 4));
  int voff1 = vrow * 128 + (((vslot + 1) * 16) ^ ((vrow & 7) << 4));
  const __bf16* kg = kbase + (size_t)krow * QKVW + kslot * 8;
  const __bf16* vg = vbase + (size_t)vrow * S_LEN + vslot * 8;

  // Q fragments, pre-scaled
  bf16x8 qf[2][4];
#pragma unroll
  for (int mi = 0; mi < 2; mi++) {
    const __bf16* qp = qkv + (size_t)(b * S_LEN + q0w + mi * 16 + lrow) * QKVW + h * HD + lg * 8;
#pragma unroll
    for (int kk = 0; kk < 4; kk++) {
      bf16x8 t = *reinterpret_cast<const bf16x8*>(qp + kk * 32);
#pragma unroll
      for (int e = 0; e < 8; e++) t[e] = (__bf16)((float)t[e] * SCL);
      qf[mi][kk] = t;
    }
  }

  f32x4 ov[2][8];
#pragma unroll
  for (int mi = 0; mi < 2; mi++)
#pragma unroll
    for (int n = 0; n < 8; n++) {
      ov[mi][n][0] = 0.f; ov[mi][n][1] = 0.f; ov[mi][n][2] = 0.f; ov[mi][n][3] = 0.f;
    }
  float m[2][4], ssum[2][4];
#pragma unroll
  for (int mi = 0; mi < 2; mi++)
#pragma unroll
    for (int jj = 0; jj < 4; jj++) { m[mi][jj] = -3.0e38f; ssum[mi][jj] = 0.f; }

  int nt = 4 * qblk + 4;
  bf16x8 kr0, kr1, vr0, vr1;

  kr0 = *reinterpret_cast<const bf16x8*>(kg);
  kr1 = *reinterpret_cast<const bf16x8*>(kg + 8);
  vr0 = *reinterpret_cast<const bf16x8*>(vg);
  vr1 = *reinterpret_cast<const bf16x8*>(vg + 8);
  *reinterpret_cast<bf16x8*>(KsB + koff0) = kr0;
  *reinterpret_cast<bf16x8*>(KsB + koff1) = kr1;
  *reinterpret_cast<bf16x8*>(VsB + voff0) = vr0;
  *reinterpret_cast<bf16x8*>(VsB + voff1) = vr1;
  __syncthreads();

  for (int t = 0;; t++) {
    int kv0 = t * 64;
    bool more = (t + 1 < nt);
    if (more) {
      int kvn = kv0 + 64;
      kr0 = *reinterpret_cast<const bf16x8*>(kg + (size_t)kvn * QKVW);
      kr1 = *reinterpret_cast<const bf16x8*>(kg + (size_t)kvn * QKVW + 8);
      vr0 = *reinterpret_cast<const bf16x8*>(vg + kvn);
      vr1 = *reinterpret_cast<const bf16x8*>(vg + kvn + 8);
    }

    bool active = (kv0 <= q0w + 31);
    if (active) {
      f32x4 sc[2][4];
#pragma unroll
      for (int mi = 0; mi < 2; mi++)
#pragma unroll
        for (int c = 0; c < 4; c++) {
          sc[mi][c][0] = 0.f; sc[mi][c][1] = 0.f; sc[mi][c][2] = 0.f; sc[mi][c][3] = 0.f;
        }
#pragma unroll
      for (int c = 0; c < 4; c++) {
        int rb = (c * 16 + lrow) * 256;
#pragma unroll
        for (int kk = 0; kk < 4; kk++) {
          bf16x8 kf = *reinterpret_cast<const bf16x8*>(KsB + rb + ((kk * 64 + lg * 16) ^ sw));
          sc[0][c] = mfma16(qf[0][kk], kf, sc[0][c]);
          sc[1][c] = mfma16(qf[1][kk], kf, sc[1][c]);
        }
      }

      bool bound = (kv0 + 64 > q0w);
      float es[2][4];
      bool anyr = false;
#pragma unroll
      for (int mi = 0; mi < 2; mi++)
#pragma unroll
        for (int jj = 0; jj < 4; jj++) {
          int qidx = q0w + mi * 16 + lg * 4 + jj;
          float s0 = sc[mi][0][jj], s1 = sc[mi][1][jj];
          float s2 = sc[mi][2][jj], s3 = sc[mi][3][jj];
          if (bound) {
            if (kv0 + lrow > qidx)      s0 = -3.0e38f;
            if (kv0 + 16 + lrow > qidx) s1 = -3.0e38f;
            if (kv0 + 32 + lrow > qidx) s2 = -3.0e38f;
            if (kv0 + 48 + lrow > qidx) s3 = -3.0e38f;
          }
          float r = fmaxf(fmaxf(s0, s1), fmaxf(s2, s3));
          r = fmaxf(r, __shfl_xor(r, 1));
          r = fmaxf(r, __shfl_xor(r, 2));
          r = fmaxf(r, __shfl_xor(r, 4));
          r = fmaxf(r, __shfl_xor(r, 8));
          float mo = m[mi][jj];
          // threshold-deferred rescale: advance m only on growth > 8 exp2
          // units; P bounded by 2^8, ssum/ov in f32 -> exact-safe.
          bool grow = (r > mo + 8.0f);
          float mn = grow ? r : mo;
          float e = grow ? exp2f(mo - r) : 1.0f;
          es[mi][jj] = e;
          anyr |= grow;
          m[mi][jj] = mn;
          float p0 = exp2f(s0 - mn), p1 = exp2f(s1 - mn);
          float p2 = exp2f(s2 - mn), p3 = exp2f(s3 - mn);
          ssum[mi][jj] = ssum[mi][jj] * e + ((p0 + p1) + (p2 + p3));
          int pr = mi * 16 + lg * 4 + jj;
          Ps[w][pr][lrow]      = (__bf16)p0;
          Ps[w][pr][16 + lrow] = (__bf16)p1;
          Ps[w][pr][32 + lrow] = (__bf16)p2;
          Ps[w][pr][48 + lrow] = (__bf16)p3;
        }
      if (__any(anyr)) {
#pragma unroll
        for (int mi = 0; mi < 2; mi++)
#pragma unroll
          for (int n = 0; n < 8; n++)
#pragma unroll
            for (int jj = 0; jj < 4; jj++) ov[mi][n][jj] *= es[mi][jj];
      }

#pragma unroll
      for (int kvs = 0; kvs < 2; kvs++) {
        bf16x8 pf0 = *reinterpret_cast<const bf16x8*>(&Ps[w][lrow][kvs * 32 + lg * 8]);
        bf16x8 pf1 = *reinterpret_cast<const bf16x8*>(&Ps[w][16 + lrow][kvs * 32 + lg * 8]);
#pragma unroll
        for (int n = 0; n < 8; n++) {
          bf16x8 vf = *reinterpret_cast<const bf16x8*>(
              VsB + (n * 16 + lrow) * 128 + ((kvs * 64 + lg * 16) ^ sw));
          ov[0][n] = mfma16(pf0, vf, ov[0][n]);
          ov[1][n] = mfma16(pf1, vf, ov[1][n]);
        }
      }
    }

    if (!more) break;
    __syncthreads();
    *reinterpret_cast<bf16x8*>(KsB + koff0) = kr0;
    *reinterpret_cast<bf16x8*>(KsB + koff1) = kr1;
    *reinterpret_cast<bf16x8*>(VsB + voff0) = vr0;
    *reinterpret_cast<bf16x8*>(VsB + voff1) = vr1;
    __syncthreads();
  }

  float rinv[2][4];
#pragma unroll
  for (int mi = 0; mi < 2; mi++)
#pragma unroll
    for (int jj = 0; jj < 4; jj++) {
      float s = ssum[mi][jj];
      s += __shfl_xor(s, 1);
      s += __shfl_xor(s, 2);
      s += __shfl_xor(s, 4);
      s += __shfl_xor(s, 8);
      rinv[mi][jj] = 1.0f / s;
    }
#pragma unroll
  for (int mi = 0; mi < 2; mi++)
#pragma unroll
    for (int n = 0; n < 8; n++)
#pragma unroll
      for (int jj = 0; jj < 4; jj++) {
        out[(size_t)(b * S_LEN + q0w + mi * 16 + lg * 4 + jj) * HIDDEN + h * HD + n * 16 + lrow] =
            (__bf16)(ov[mi][n][jj] * rinv[mi][jj]);
      }
}

// ---------------------------------------------------------------------------
// Workspace layout (bytes), total 142606336:
//   h_bf / a_buf (aliased) @ 0          33554432   bf16 [4096][4096]
//   Wt (qkv^T, later Wo^T) @ 33554432   50331648   bf16 [6144][4096]
//   qkv_buf                @ 83886080   50331648   bf16 [4096][6144]
//   vt_buf                 @ 134217728   8388608   bf16 [16][128][2048]
// ---------------------------------------------------------------------------
extern "C" void kernel_launch(void* const* d_in, const int* in_sizes, int n_in,
                              void* d_out, int out_size, void* d_ws, size_t ws_size,
                              hipStream_t stream) {
  const float* hidden = (const float*)d_in[0];
  const int* posids   = (const int*)d_in[1];
  const float* Wq     = (const float*)d_in[2];
  const float* Wk     = (const float*)d_in[3];
  const float* Wv     = (const float*)d_in[4];
  const float* Wo     = (const float*)d_in[5];
  float* out = (float*)d_out;

  char* ws = (char*)d_ws;
  __bf16* h_bf    = (__bf16*)(ws + 0);
  __bf16* a_buf   = h_bf;  // aliased: h last read by QKV GEMMs, before attn writes
  __bf16* Wt      = (__bf16*)(ws + 33554432);
  __bf16* qkv_buf = (__bf16*)(ws + 83886080);
  __bf16* vt_buf  = (__bf16*)(ws + 134217728);

  dim3 b256(256), b328(32, 8), b512(512);

  // 1. hidden -> bf16
  cvt_kernel<<<dim3(MROWS * HIDDEN / (256 * 8)), b256, 0, stream>>>(hidden, h_bf, MROWS * HIDDEN);

  // 2. fused weight transpose: Wt = [Wq^T ; Wk^T ; Wv^T]  [6144][4096]
  tcvt3_kernel<<<dim3(128, 128, 3), b328, 0, stream>>>(Wq, Wk, Wv, Wt);

  // 3a. QKV main: cols [0,4096) via 256^2 tiles -> 256 blocks (1 round)
  gemm256<__bf16><<<dim3(256), b512, 0, stream>>>(
      h_bf, Wt, qkv_buf, HIDDEN, QKVW, 4096 / 256);
  // 3b. QKV tail: cols [4096,6144) via 256x128 tiles -> 256 blocks
  gemm128<__bf16><<<dim3(256), b512, 0, stream>>>(
      h_bf, Wt + (size_t)4096 * 4096, qkv_buf + 4096, HIDDEN, QKVW, 2048 / 128);

  // 4. RoPE on q,k (in fused buffer), vectorized
  rope_kernel<<<dim3(MROWS), b256, 0, stream>>>(qkv_buf, posids);

  // 5. V^T
  tvt_kernel<<<dim3(HD / 32, S_LEN / 32, BATCH * NKV), b328, 0, stream>>>(qkv_buf, vt_buf);

  // 6. attention -> a_buf  (512 blocks, heavy-first, 2 blocks/CU)
  attn_kernel<<<dim3(8 * NH * BATCH), b512, 0, stream>>>(qkv_buf, vt_buf, a_buf);

  // 7. Wo^T (reuse Wt)
  tcvt_f32<<<dim3(HIDDEN / 32, HIDDEN / 32), b328, 0, stream>>>(Wo, Wt, HIDDEN, HIDDEN);

  // 8. out = a @ Wo  (fp32 out; 256 blocks = 1 balanced round)
  gemm256<float><<<dim3(256), b512, 0, stream>>>(
      a_buf, Wt, out, HIDDEN, HIDDEN, HIDDEN / 256);
}

// Round 10
// 485.898 us; speedup vs baseline: 1.2621x; 1.0968x over previous
//
#include <hip/hip_runtime.h>
#include <hip/hip_bf16.h>
#include <math.h>

#define HIDDEN 4096
#define NH 32
#define NKV 8
#define HD 128
#define S_LEN 2048
#define BATCH 2
#define MROWS (BATCH * S_LEN)  // 4096
#define QKVW 6144              // fused q|k|v row width

typedef __attribute__((ext_vector_type(8))) __bf16 bf16x8;
typedef __attribute__((ext_vector_type(4))) float f32x4;

__device__ __forceinline__ f32x4 mfma16(bf16x8 a, bf16x8 b, f32x4 c) {
  return __builtin_amdgcn_mfma_f32_16x16x32_bf16(a, b, c, 0, 0, 0);
}

// async global->LDS, 16B/lane; LDS dest = wave-uniform base, HW adds lane*16.
__device__ __forceinline__ void gload16(const __bf16* g, const __bf16* l) {
  __builtin_amdgcn_global_load_lds(
      (const __attribute__((address_space(1))) void*)g,
      (__attribute__((address_space(3))) void*)l, 16, 0, 0);
}

#define SBAR()                          \
  do {                                  \
    __builtin_amdgcn_sched_barrier(0);  \
    __builtin_amdgcn_s_barrier();       \
    __builtin_amdgcn_sched_barrier(0);  \
  } while (0)

// ---------------------------------------------------------------------------
// fp32 -> bf16 elementwise convert (vectorized)
// ---------------------------------------------------------------------------
__global__ __launch_bounds__(256) void cvt_kernel(const float* __restrict__ in,
                                                  __bf16* __restrict__ out, int n) {
  int i = (blockIdx.x * 256 + threadIdx.x) * 8;
  if (i >= n) return;
  float4 a = *reinterpret_cast<const float4*>(in + i);
  float4 b = *reinterpret_cast<const float4*>(in + i + 4);
  bf16x8 t;
  t[0] = (__bf16)a.x; t[1] = (__bf16)a.y; t[2] = (__bf16)a.z; t[3] = (__bf16)a.w;
  t[4] = (__bf16)b.x; t[5] = (__bf16)b.y; t[6] = (__bf16)b.z; t[7] = (__bf16)b.w;
  *reinterpret_cast<bf16x8*>(out + i) = t;
}

// ---------------------------------------------------------------------------
// Fused weight transpose+convert: z=0 Wq (4096 cols), z=1 Wk, z=2 Wv (1024).
// ---------------------------------------------------------------------------
__global__ __launch_bounds__(256) void tcvt3_kernel(const float* __restrict__ Wq,
                                                    const float* __restrict__ Wk,
                                                    const float* __restrict__ Wv,
                                                    __bf16* __restrict__ Wt) {
  __shared__ float t[32][33];
  int z = blockIdx.z;
  const float* in;
  __bf16* out;
  int C;
  if (z == 0)      { in = Wq; out = Wt;                         C = 4096; }
  else if (z == 1) { in = Wk; out = Wt + (size_t)4096 * 4096;   C = 1024; }
  else             { in = Wv; out = Wt + (size_t)5120 * 4096;   C = 1024; }
  if ((int)blockIdx.x * 32 >= C) return;
  int tx = threadIdx.x, ty = threadIdx.y;
  int r0 = blockIdx.y * 32, c0 = blockIdx.x * 32;
#pragma unroll
  for (int i = 0; i < 4; i++)
    t[ty + i * 8][tx] = in[(size_t)(r0 + ty + i * 8) * C + c0 + tx];
  __syncthreads();
#pragma unroll
  for (int i = 0; i < 4; i++)
    out[(size_t)(c0 + ty + i * 8) * 4096 + r0 + tx] = (__bf16)t[tx][ty + i * 8];
}

// single transpose for Wo
__global__ __launch_bounds__(256) void tcvt_f32(const float* __restrict__ in,
                                                __bf16* __restrict__ out,
                                                int R, int C) {
  __shared__ float t[32][33];
  int tx = threadIdx.x, ty = threadIdx.y;
  int r0 = blockIdx.y * 32, c0 = blockIdx.x * 32;
#pragma unroll
  for (int i = 0; i < 4; i++)
    t[ty + i * 8][tx] = in[(size_t)(r0 + ty + i * 8) * C + c0 + tx];
  __syncthreads();
#pragma unroll
  for (int i = 0; i < 4; i++)
    out[(size_t)(c0 + ty + i * 8) * R + r0 + tx] = (__bf16)t[tx][ty + i * 8];
}

// ---------------------------------------------------------------------------
// V transpose: qkv [B*S][QKVW] (v at col 5120 + kvh*HD) -> vt [B*NKV][HD][S].
// ---------------------------------------------------------------------------
__global__ __launch_bounds__(256) void tvt_kernel(const __bf16* __restrict__ qkv,
                                                  __bf16* __restrict__ vt) {
  __shared__ __bf16 t[32][33];
  int tx = threadIdx.x, ty = threadIdx.y;
  int z = blockIdx.z;
  int b = z >> 3, kvh = z & 7;
  int kv0 = blockIdx.y * 32, d0 = blockIdx.x * 32;
#pragma unroll
  for (int i = 0; i < 4; i++)
    t[ty + i * 8][tx] =
        qkv[(size_t)(b * S_LEN + kv0 + ty + i * 8) * QKVW + 5120 + kvh * HD + d0 + tx];
  __syncthreads();
#pragma unroll
  for (int i = 0; i < 4; i++)
    vt[((size_t)z * HD + d0 + ty + i * 8) * S_LEN + kv0 + tx] = t[tx][ty + i * 8];
}

// ---------------------------------------------------------------------------
// 256x256 8-phase GEMM (m201-style): C[M,N] = A * Bt^T, ldc-strided output.
// ---------------------------------------------------------------------------
template<typename CT>
__global__ __launch_bounds__(512, 2) void gemm256(const __bf16* __restrict__ A,
                                                  const __bf16* __restrict__ Bt,
                                                  CT* __restrict__ C,
                                                  int K, int ldc, int nbx) {
  __shared__ char lds[131072];
  const int tid = threadIdx.x;
  const int l = tid & 63, w = tid >> 6;
  const int lrow = l & 15, lg = l >> 4;
  const int sw = (lrow & 7) << 4;

  int nwg = gridDim.x;
  int swz = (blockIdx.x & 7) * (nwg >> 3) + (blockIdx.x >> 3);
  int bx = swz % nbx, by = swz / nbx;
  int m0 = by * 256, n0 = bx * 256;

  const int rA = w * 8 + (l >> 3);
  const int csw = ((l & 7) ^ (l >> 3)) * 8;  // inverse-swizzled source col
  const __bf16* As_[2][2];
  const __bf16* Bs_[2][2];
#pragma unroll
  for (int h = 0; h < 2; h++)
#pragma unroll
    for (int p = 0; p < 2; p++) {
      As_[h][p] = A + (size_t)(m0 + h * 128 + p * 64 + rA) * K + csw;
      Bs_[h][p] = Bt + (size_t)(n0 + h * 128 + p * 64 + rA) * K + csw;
    }

  auto stageA = [&](int par, int h, int kt) {
#pragma unroll
    for (int p = 0; p < 2; p++)
      gload16(As_[h][p] + kt * 64,
              (const __bf16*)(lds + par * 32768 + h * 16384 + p * 8192 + w * 1024));
  };
  auto stageB = [&](int par, int h, int kt) {
#pragma unroll
    for (int p = 0; p < 2; p++)
      gload16(Bs_[h][p] + kt * 64,
              (const __bf16*)(lds + 65536 + par * 32768 + h * 16384 + p * 8192 + w * 1024));
  };

  const int arbase = (w >> 2) * 64 + lrow;
  const int brbase = (w & 3) * 32 + lrow;

  bf16x8 aA[4][2];
  bf16x8 bB[2][2][2];

  auto readA = [&](int par, int ah) {
#pragma unroll
    for (int i = 0; i < 4; i++)
#pragma unroll
      for (int kk = 0; kk < 2; kk++)
        aA[i][kk] = *reinterpret_cast<const bf16x8*>(
            lds + par * 32768 + (arbase + i * 16 + ah * 128) * 128 +
            ((kk * 64 + lg * 16) ^ sw));
  };
  auto readB = [&](int par, int bh) {
#pragma unroll
    for (int j = 0; j < 2; j++)
#pragma unroll
      for (int kk = 0; kk < 2; kk++)
        bB[bh][j][kk] = *reinterpret_cast<const bf16x8*>(
            lds + 65536 + par * 32768 + (brbase + j * 16 + bh * 128) * 128 +
            ((kk * 64 + lg * 16) ^ sw));
  };

  f32x4 acc[8][4];
#pragma unroll
  for (int i = 0; i < 8; i++)
#pragma unroll
    for (int j = 0; j < 4; j++) {
      acc[i][j][0] = 0.f; acc[i][j][1] = 0.f; acc[i][j][2] = 0.f; acc[i][j][3] = 0.f;
    }

  const int NT = K >> 6;

  stageA(0, 0, 0); stageA(0, 1, 0); stageB(0, 0, 0); stageB(0, 1, 0);
  stageA(1, 0, 1); stageB(1, 0, 1);
  __builtin_amdgcn_sched_barrier(0);
  asm volatile("s_waitcnt vmcnt(4)" ::: "memory");
  SBAR();

  for (int t = 0; t < NT; t++) {
    const int par = t & 1, npar = par ^ 1;
    const int t1 = (t + 1 < NT) ? t + 1 : 0;
    const int t2 = (t + 2 < NT) ? t + 2 : 0;

#define MFMA_QUAD(AH, BH)                                                   \
  __builtin_amdgcn_s_setprio(1);                                            \
  _Pragma("unroll") for (int i4 = 0; i4 < 4; i4++)                          \
      _Pragma("unroll") for (int j2 = 0; j2 < 2; j2++)                      \
          _Pragma("unroll") for (int kk = 0; kk < 2; kk++)                  \
              acc[(AH)*4 + i4][(BH)*2 + j2] =                               \
                  mfma16(aA[i4][kk], bB[BH][j2][kk], acc[(AH)*4 + i4][(BH)*2 + j2]); \
  __builtin_amdgcn_s_setprio(0);

    readA(par, 0);
    readB(par, 0);
    stageA(npar, 1, t1);
    SBAR();
    MFMA_QUAD(0, 0);
    SBAR();
    readB(par, 1);
    stageB(npar, 1, t1);
    SBAR();
    MFMA_QUAD(0, 1);
    SBAR();
    readA(par, 1);
    stageA(par, 0, t2);
    SBAR();
    MFMA_QUAD(1, 0);
    SBAR();
    stageB(par, 0, t2);
    SBAR();
    MFMA_QUAD(1, 1);
    __builtin_amdgcn_sched_barrier(0);
    asm volatile("s_waitcnt vmcnt(4)" ::: "memory");
    SBAR();
#undef MFMA_QUAD
  }

#pragma unroll
  for (int i = 0; i < 8; i++) {
    int row = m0 + (w >> 2) * 64 + (i & 3) * 16 + (i >> 2) * 128 + lg * 4;
#pragma unroll
    for (int j = 0; j < 4; j++) {
      int col = n0 + (w & 3) * 32 + (j & 1) * 16 + (j >> 1) * 128 + lrow;
#pragma unroll
      for (int jj = 0; jj < 4; jj++)
        C[(size_t)(row + jj) * ldc + col] = (CT)acc[i][j][jj];
    }
  }
}

// ---------------------------------------------------------------------------
// 256x128 GEMM, 2 phases/K-tile, ldc-strided output.
// ---------------------------------------------------------------------------
template<typename CT>
__global__ __launch_bounds__(512, 2) void gemm128(const __bf16* __restrict__ A,
                                                  const __bf16* __restrict__ Bt,
                                                  CT* __restrict__ C,
                                                  int K, int ldc, int nbx) {
  __shared__ char lds[98304];
  const int tid = threadIdx.x;
  const int l = tid & 63, w = tid >> 6;
  const int lrow = l & 15, lg = l >> 4;
  const int sw = (lrow & 7) << 4;

  int nwg = gridDim.x;
  int swz = (blockIdx.x & 7) * (nwg >> 3) + (blockIdx.x >> 3);
  int bx = swz % nbx, by = swz / nbx;
  int m0 = by * 256, n0 = bx * 128;

  const int rA = w * 8 + (l >> 3);
  const int csw = ((l & 7) ^ (l >> 3)) * 8;
  const __bf16* As_[2][2];
  const __bf16* Bs_[2];
#pragma unroll
  for (int h = 0; h < 2; h++)
#pragma unroll
    for (int p = 0; p < 2; p++)
      As_[h][p] = A + (size_t)(m0 + h * 128 + p * 64 + rA) * K + csw;
#pragma unroll
  for (int p = 0; p < 2; p++)
    Bs_[p] = Bt + (size_t)(n0 + p * 64 + rA) * K + csw;

  auto stageA = [&](int par, int h, int kt) {
#pragma unroll
    for (int p = 0; p < 2; p++)
      gload16(As_[h][p] + kt * 64,
              (const __bf16*)(lds + par * 32768 + h * 16384 + p * 8192 + w * 1024));
  };
  auto stageB = [&](int par, int kt) {
#pragma unroll
    for (int p = 0; p < 2; p++)
      gload16(Bs_[p] + kt * 64,
              (const __bf16*)(lds + 65536 + par * 16384 + p * 8192 + w * 1024));
  };

  const int arbase = (w >> 2) * 64 + lrow;
  const int brbase = (w & 3) * 32 + lrow;

  bf16x8 aA[4][2];
  bf16x8 bB[2][2];

  auto readA = [&](int par, int ah) {
#pragma unroll
    for (int i = 0; i < 4; i++)
#pragma unroll
      for (int kk = 0; kk < 2; kk++)
        aA[i][kk] = *reinterpret_cast<const bf16x8*>(
            lds + par * 32768 + (arbase + i * 16 + ah * 128) * 128 +
            ((kk * 64 + lg * 16) ^ sw));
  };
  auto readB = [&](int par) {
#pragma unroll
    for (int j = 0; j < 2; j++)
#pragma unroll
      for (int kk = 0; kk < 2; kk++)
        bB[j][kk] = *reinterpret_cast<const bf16x8*>(
            lds + 65536 + par * 16384 + (brbase + j * 16) * 128 +
            ((kk * 64 + lg * 16) ^ sw));
  };

  f32x4 acc[8][2];
#pragma unroll
  for (int i = 0; i < 8; i++)
#pragma unroll
    for (int j = 0; j < 2; j++) {
      acc[i][j][0] = 0.f; acc[i][j][1] = 0.f; acc[i][j][2] = 0.f; acc[i][j][3] = 0.f;
    }

  const int NT = K >> 6;

  stageA(0, 0, 0); stageA(0, 1, 0); stageB(0, 0);
  stageA(1, 0, 1);
  __builtin_amdgcn_sched_barrier(0);
  asm volatile("s_waitcnt vmcnt(2)" ::: "memory");
  SBAR();

  for (int t = 0; t < NT; t++) {
    const int par = t & 1, npar = par ^ 1;
    const int t1 = (t + 1 < NT) ? t + 1 : 0;
    const int t2 = (t + 2 < NT) ? t + 2 : 0;

#define MFMA_HALF(AH)                                                        \
  __builtin_amdgcn_s_setprio(1);                                             \
  _Pragma("unroll") for (int i4 = 0; i4 < 4; i4++)                           \
      _Pragma("unroll") for (int j2 = 0; j2 < 2; j2++)                       \
          _Pragma("unroll") for (int kk = 0; kk < 2; kk++)                   \
              acc[(AH)*4 + i4][j2] =                                         \
                  mfma16(aA[i4][kk], bB[j2][kk], acc[(AH)*4 + i4][j2]);      \
  __builtin_amdgcn_s_setprio(0);

    readA(par, 0);
    readB(par);
    stageA(npar, 1, t1);
    stageB(npar, t1);
    SBAR();
    MFMA_HALF(0);
    SBAR();
    readA(par, 1);
    stageA(par, 0, t2);
    SBAR();
    MFMA_HALF(1);
    __builtin_amdgcn_sched_barrier(0);
    asm volatile("s_waitcnt vmcnt(2)" ::: "memory");
    SBAR();
#undef MFMA_HALF
  }

#pragma unroll
  for (int i = 0; i < 8; i++) {
    int row = m0 + (w >> 2) * 64 + (i & 3) * 16 + (i >> 2) * 128 + lg * 4;
#pragma unroll
    for (int j = 0; j < 2; j++) {
      int col = n0 + (w & 3) * 32 + j * 16 + lrow;
#pragma unroll
      for (int jj = 0; jj < 4; jj++)
        C[(size_t)(row + jj) * ldc + col] = (CT)acc[i][j][jj];
    }
  }
}

// ---------------------------------------------------------------------------
// RoPE, in-place on fused qkv buffer, vectorized.
// ---------------------------------------------------------------------------
__global__ __launch_bounds__(256) void rope_kernel(__bf16* __restrict__ qkv,
                                                   const int* __restrict__ pos) {
  int row = blockIdx.x;
  int t = threadIdx.x;
  float p = (float)pos[row];
  __bf16* rbase = qkv + (size_t)row * QKVW;

  {
    int head = t >> 3, chunk = t & 7;
    __bf16* base = rbase + head * HD + chunk * 8;
    bf16x8 x1 = *reinterpret_cast<const bf16x8*>(base);
    bf16x8 x2 = *reinterpret_cast<const bf16x8*>(base + 64);
    bf16x8 o1, o2;
#pragma unroll
    for (int e = 0; e < 8; e++) {
      float ang = p * exp2f(-0.20762050f * (float)(chunk * 8 + e));
      float s, c;
      __sincosf(ang, &s, &c);
      float a = (float)x1[e], b2 = (float)x2[e];
      o1[e] = (__bf16)(a * c - b2 * s);
      o2[e] = (__bf16)(b2 * c + a * s);
    }
    *reinterpret_cast<bf16x8*>(base) = o1;
    *reinterpret_cast<bf16x8*>(base + 64) = o2;
  }
  if (t < 64) {
    int head = t >> 3, chunk = t & 7;
    __bf16* base = rbase + 4096 + head * HD + chunk * 8;
    bf16x8 x1 = *reinterpret_cast<const bf16x8*>(base);
    bf16x8 x2 = *reinterpret_cast<const bf16x8*>(base + 64);
    bf16x8 o1, o2;
#pragma unroll
    for (int e = 0; e < 8; e++) {
      float ang = p * exp2f(-0.20762050f * (float)(chunk * 8 + e));
      float s, c;
      __sincosf(ang, &s, &c);
      float a = (float)x1[e], b2 = (float)x2[e];
      o1[e] = (__bf16)(a * c - b2 * s);
      o2[e] = (__bf16)(b2 * c + a * s);
    }
    *reinterpret_cast<bf16x8*>(base) = o1;
    *reinterpret_cast<bf16x8*>(base + 64) = o2;
  }
}

// ---------------------------------------------------------------------------
// Flash attention, causal, GQA. 512 blocks (2/CU co-resident), heavy-first.
// 8 waves x 32 q-rows, KVBLK=64, K/V^T reg-staged to XOR-swizzled LDS, T14
// async-stage split. Online softmax with guarded reduce: per-lane growth
// check -> __any -> shfl reduce + rescale ONLY when some row max grew >8
// exp2 units (rare). SINGLE exp2/P-write block after the branch (no code
// duplication -> no scratch spills; R8 lesson). P <= 2^8, ssum/ov f32.
// ---------------------------------------------------------------------------
__global__ __launch_bounds__(512) void attn_kernel(const __bf16* __restrict__ qkv,
                                                   const __bf16* __restrict__ vt,
                                                   __bf16* __restrict__ out) {
  __shared__ __bf16 Ks[64 * 128];      // [kv][d], swizzled, 16 KB
  __shared__ __bf16 Vs[128 * 64];      // [d][kv], swizzled, 16 KB
  __shared__ __bf16 Ps[8][32][68];     // per-wave P, padded, 34 KB

  int tid = threadIdx.x;
  int l = tid & 63, w = tid >> 6;
  int bid = blockIdx.x;
  int qblk = 7 - (bid >> 6);           // heavy blocks first
  int rem = bid & 63;
  int h = rem & 31, b = rem >> 5;
  int kvh = h >> 2;
  int q0w = qblk * 256 + w * 32;
  int lrow = l & 15, lg = l >> 4;
  int sw = (lrow & 7) << 4;
  const float SCL = 0.08838834764831845f * 1.4426950408889634f;  // 1/sqrt(128)*log2e

  const __bf16* kbase = qkv + (size_t)(b * S_LEN) * QKVW + 4096 + kvh * HD;
  const __bf16* vbase = vt + ((size_t)(b * NKV + kvh) * HD) * S_LEN;

  int krow = tid >> 3;
  int kslot = (tid & 7) * 2;
  int vrow = tid >> 2;
  int vslot = (tid & 3) * 2;
  char* KsB = (char*)Ks;
  char* VsB = (char*)Vs;
  int koff0 = krow * 256 + ((kslot * 16) ^ ((krow & 7) << 4));
  int koff1 = krow * 256 + (((kslot + 1) * 16) ^ ((krow & 7) << 4));
  int voff0 = vrow * 128 + ((vslot * 16) ^ ((vrow & 7) << 4));
  int voff1 = vrow * 128 + (((vslot + 1) * 16) ^ ((vrow & 7) << 4));
  const __bf16* kg = kbase + (size_t)krow * QKVW + kslot * 8;
  const __bf16* vg = vbase + (size_t)vrow * S_LEN + vslot * 8;

  // Q fragments, pre-scaled
  bf16x8 qf[2][4];
#pragma unroll
  for (int mi = 0; mi < 2; mi++) {
    const __bf16* qp = qkv + (size_t)(b * S_LEN + q0w + mi * 16 + lrow) * QKVW + h * HD + lg * 8;
#pragma unroll
    for (int kk = 0; kk < 4; kk++) {
      bf16x8 t = *reinterpret_cast<const bf16x8*>(qp + kk * 32);
#pragma unroll
      for (int e = 0; e < 8; e++) t[e] = (__bf16)((float)t[e] * SCL);
      qf[mi][kk] = t;
    }
  }

  f32x4 ov[2][8];
#pragma unroll
  for (int mi = 0; mi < 2; mi++)
#pragma unroll
    for (int n = 0; n < 8; n++) {
      ov[mi][n][0] = 0.f; ov[mi][n][1] = 0.f; ov[mi][n][2] = 0.f; ov[mi][n][3] = 0.f;
    }
  float m[2][4], ssum[2][4];
#pragma unroll
  for (int mi = 0; mi < 2; mi++)
#pragma unroll
    for (int jj = 0; jj < 4; jj++) { m[mi][jj] = -3.0e38f; ssum[mi][jj] = 0.f; }

  int nt = 4 * qblk + 4;
  bf16x8 kr0, kr1, vr0, vr1;

  kr0 = *reinterpret_cast<const bf16x8*>(kg);
  kr1 = *reinterpret_cast<const bf16x8*>(kg + 8);
  vr0 = *reinterpret_cast<const bf16x8*>(vg);
  vr1 = *reinterpret_cast<const bf16x8*>(vg + 8);
  *reinterpret_cast<bf16x8*>(KsB + koff0) = kr0;
  *reinterpret_cast<bf16x8*>(KsB + koff1) = kr1;
  *reinterpret_cast<bf16x8*>(VsB + voff0) = vr0;
  *reinterpret_cast<bf16x8*>(VsB + voff1) = vr1;
  __syncthreads();

  for (int t = 0;; t++) {
    int kv0 = t * 64;
    bool more = (t + 1 < nt);
    if (more) {
      int kvn = kv0 + 64;
      kr0 = *reinterpret_cast<const bf16x8*>(kg + (size_t)kvn * QKVW);
      kr1 = *reinterpret_cast<const bf16x8*>(kg + (size_t)kvn * QKVW + 8);
      vr0 = *reinterpret_cast<const bf16x8*>(vg + kvn);
      vr1 = *reinterpret_cast<const bf16x8*>(vg + kvn + 8);
    }

    bool active = (kv0 <= q0w + 31);
    if (active) {
      f32x4 sc[2][4];
#pragma unroll
      for (int mi = 0; mi < 2; mi++)
#pragma unroll
        for (int c = 0; c < 4; c++) {
          sc[mi][c][0] = 0.f; sc[mi][c][1] = 0.f; sc[mi][c][2] = 0.f; sc[mi][c][3] = 0.f;
        }
#pragma unroll
      for (int c = 0; c < 4; c++) {
        int rb = (c * 16 + lrow) * 256;
#pragma unroll
        for (int kk = 0; kk < 4; kk++) {
          bf16x8 kf = *reinterpret_cast<const bf16x8*>(KsB + rb + ((kk * 64 + lg * 16) ^ sw));
          sc[0][c] = mfma16(qf[0][kk], kf, sc[0][c]);
          sc[1][c] = mfma16(qf[1][kk], kf, sc[1][c]);
        }
      }

      // causal mask
      bool bound = (kv0 + 64 > q0w);
      if (bound) {
#pragma unroll
        for (int mi = 0; mi < 2; mi++)
#pragma unroll
          for (int jj = 0; jj < 4; jj++) {
            int qidx = q0w + mi * 16 + lg * 4 + jj;
            if (kv0 + lrow > qidx)      sc[mi][0][jj] = -3.0e38f;
            if (kv0 + 16 + lrow > qidx) sc[mi][1][jj] = -3.0e38f;
            if (kv0 + 32 + lrow > qidx) sc[mi][2][jj] = -3.0e38f;
            if (kv0 + 48 + lrow > qidx) sc[mi][3][jj] = -3.0e38f;
          }
      }

      // per-lane growth check (cheap); reduce+rescale only when needed
      float lm[2][4];
      bool lanegrow = false;
#pragma unroll
      for (int mi = 0; mi < 2; mi++)
#pragma unroll
        for (int jj = 0; jj < 4; jj++) {
          lm[mi][jj] = fmaxf(fmaxf(sc[mi][0][jj], sc[mi][1][jj]),
                             fmaxf(sc[mi][2][jj], sc[mi][3][jj]));
          lanegrow |= (lm[mi][jj] > m[mi][jj] + 8.0f);
        }

      if (__any(lanegrow)) {
        // rare slow path: full row-max reduce, update m, rescale ov & ssum
        float es[2][4];
#pragma unroll
        for (int mi = 0; mi < 2; mi++)
#pragma unroll
          for (int jj = 0; jj < 4; jj++) {
            float r = lm[mi][jj];
            r = fmaxf(r, __shfl_xor(r, 1));
            r = fmaxf(r, __shfl_xor(r, 2));
            r = fmaxf(r, __shfl_xor(r, 4));
            r = fmaxf(r, __shfl_xor(r, 8));
            float mo = m[mi][jj];
            bool grow = (r > mo + 8.0f);
            float mn = grow ? r : mo;
            float e = grow ? exp2f(mo - r) : 1.0f;
            es[mi][jj] = e;
            m[mi][jj] = mn;
            ssum[mi][jj] *= e;
          }
#pragma unroll
        for (int mi = 0; mi < 2; mi++)
#pragma unroll
          for (int n = 0; n < 8; n++)
#pragma unroll
            for (int jj = 0; jj < 4; jj++) ov[mi][n][jj] *= es[mi][jj];
      }

      // single exp2 / P-write path (no duplication -> no spills)
#pragma unroll
      for (int mi = 0; mi < 2; mi++)
#pragma unroll
        for (int jj = 0; jj < 4; jj++) {
          float mn = m[mi][jj];
          float p0 = exp2f(sc[mi][0][jj] - mn), p1 = exp2f(sc[mi][1][jj] - mn);
          float p2 = exp2f(sc[mi][2][jj] - mn), p3 = exp2f(sc[mi][3][jj] - mn);
          ssum[mi][jj] += (p0 + p1) + (p2 + p3);
          int pr = mi * 16 + lg * 4 + jj;
          Ps[w][pr][lrow]      = (__bf16)p0;
          Ps[w][pr][16 + lrow] = (__bf16)p1;
          Ps[w][pr][32 + lrow] = (__bf16)p2;
          Ps[w][pr][48 + lrow] = (__bf16)p3;
        }

#pragma unroll
      for (int kvs = 0; kvs < 2; kvs++) {
        bf16x8 pf0 = *reinterpret_cast<const bf16x8*>(&Ps[w][lrow][kvs * 32 + lg * 8]);
        bf16x8 pf1 = *reinterpret_cast<const bf16x8*>(&Ps[w][16 + lrow][kvs * 32 + lg * 8]);
#pragma unroll
        for (int n = 0; n < 8; n++) {
          bf16x8 vf = *reinterpret_cast<const bf16x8*>(
              VsB + (n * 16 + lrow) * 128 + ((kvs * 64 + lg * 16) ^ sw));
          ov[0][n] = mfma16(pf0, vf, ov[0][n]);
          ov[1][n] = mfma16(pf1, vf, ov[1][n]);
        }
      }
    }

    if (!more) break;
    __syncthreads();
    *reinterpret_cast<bf16x8*>(KsB + koff0) = kr0;
    *reinterpret_cast<bf16x8*>(KsB + koff1) = kr1;
    *reinterpret_cast<bf16x8*>(VsB + voff0) = vr0;
    *reinterpret_cast<bf16x8*>(VsB + voff1) = vr1;
    __syncthreads();
  }

  float rinv[2][4];
#pragma unroll
  for (int mi = 0; mi < 2; mi++)
#pragma unroll
    for (int jj = 0; jj < 4; jj++) {
      float s = ssum[mi][jj];
      s += __shfl_xor(s, 1);
      s += __shfl_xor(s, 2);
      s += __shfl_xor(s, 4);
      s += __shfl_xor(s, 8);
      rinv[mi][jj] = 1.0f / s;
    }
#pragma unroll
  for (int mi = 0; mi < 2; mi++)
#pragma unroll
    for (int n = 0; n < 8; n++)
#pragma unroll
      for (int jj = 0; jj < 4; jj++) {
        out[(size_t)(b * S_LEN + q0w + mi * 16 + lg * 4 + jj) * HIDDEN + h * HD + n * 16 + lrow] =
            (__bf16)(ov[mi][n][jj] * rinv[mi][jj]);
      }
}

// ---------------------------------------------------------------------------
// Workspace layout (bytes), total 142606336:
//   h_bf / a_buf (aliased) @ 0          33554432   bf16 [4096][4096]
//   Wt (qkv^T, later Wo^T) @ 33554432   50331648   bf16 [6144][4096]
//   qkv_buf                @ 83886080   50331648   bf16 [4096][6144]
//   vt_buf                 @ 134217728   8388608   bf16 [16][128][2048]
// ---------------------------------------------------------------------------
extern "C" void kernel_launch(void* const* d_in, const int* in_sizes, int n_in,
                              void* d_out, int out_size, void* d_ws, size_t ws_size,
                              hipStream_t stream) {
  const float* hidden = (const float*)d_in[0];
  const int* posids   = (const int*)d_in[1];
  const float* Wq     = (const float*)d_in[2];
  const float* Wk     = (const float*)d_in[3];
  const float* Wv     = (const float*)d_in[4];
  const float* Wo     = (const float*)d_in[5];
  float* out = (float*)d_out;

  char* ws = (char*)d_ws;
  __bf16* h_bf    = (__bf16*)(ws + 0);
  __bf16* a_buf   = h_bf;  // aliased: h last read by QKV GEMMs, before attn writes
  __bf16* Wt      = (__bf16*)(ws + 33554432);
  __bf16* qkv_buf = (__bf16*)(ws + 83886080);
  __bf16* vt_buf  = (__bf16*)(ws + 134217728);

  dim3 b256(256), b328(32, 8), b512(512);

  // 1. hidden -> bf16
  cvt_kernel<<<dim3(MROWS * HIDDEN / (256 * 8)), b256, 0, stream>>>(hidden, h_bf, MROWS * HIDDEN);

  // 2. fused weight transpose: Wt = [Wq^T ; Wk^T ; Wv^T]  [6144][4096]
  tcvt3_kernel<<<dim3(128, 128, 3), b328, 0, stream>>>(Wq, Wk, Wv, Wt);

  // 3a. QKV main: cols [0,4096) via 256^2 tiles -> 256 blocks (1 round)
  gemm256<__bf16><<<dim3(256), b512, 0, stream>>>(
      h_bf, Wt, qkv_buf, HIDDEN, QKVW, 4096 / 256);
  // 3b. QKV tail: cols [4096,6144) via 256x128 tiles -> 256 blocks
  gemm128<__bf16><<<dim3(256), b512, 0, stream>>>(
      h_bf, Wt + (size_t)4096 * 4096, qkv_buf + 4096, HIDDEN, QKVW, 2048 / 128);

  // 4. RoPE on q,k (in fused buffer), vectorized
  rope_kernel<<<dim3(MROWS), b256, 0, stream>>>(qkv_buf, posids);

  // 5. V^T
  tvt_kernel<<<dim3(HD / 32, S_LEN / 32, BATCH * NKV), b328, 0, stream>>>(qkv_buf, vt_buf);

  // 6. attention -> a_buf  (512 blocks, heavy-first, 2 blocks/CU)
  attn_kernel<<<dim3(8 * NH * BATCH), b512, 0, stream>>>(qkv_buf, vt_buf, a_buf);

  // 7. Wo^T (reuse Wt)
  tcvt_f32<<<dim3(HIDDEN / 32, HIDDEN / 32), b328, 0, stream>>>(Wo, Wt, HIDDEN, HIDDEN);

  // 8. out = a @ Wo  (fp32 out; 256 blocks = 1 balanced round)
  gemm256<float><<<dim3(256), b512, 0, stream>>>(
      a_buf, Wt, out, HIDDEN, HIDDEN, HIDDEN / 256);
}

// Round 11
// 468.176 us; speedup vs baseline: 1.3098x; 1.0379x over previous
//
#include <hip/hip_runtime.h>
#include <hip/hip_bf16.h>
#include <math.h>

#define HIDDEN 4096
#define NH 32
#define NKV 8
#define HD 128
#define S_LEN 2048
#define BATCH 2
#define MROWS (BATCH * S_LEN)  // 4096
#define QKVW 6144              // fused q|k|v row width

typedef __attribute__((ext_vector_type(8))) __bf16 bf16x8;
typedef __attribute__((ext_vector_type(4))) float f32x4;

__device__ __forceinline__ f32x4 mfma16(bf16x8 a, bf16x8 b, f32x4 c) {
  return __builtin_amdgcn_mfma_f32_16x16x32_bf16(a, b, c, 0, 0, 0);
}

// async global->LDS, 16B/lane; LDS dest = wave-uniform base, HW adds lane*16.
__device__ __forceinline__ void gload16(const __bf16* g, const __bf16* l) {
  __builtin_amdgcn_global_load_lds(
      (const __attribute__((address_space(1))) void*)g,
      (__attribute__((address_space(3))) void*)l, 16, 0, 0);
}

#define SBAR()                          \
  do {                                  \
    __builtin_amdgcn_sched_barrier(0);  \
    __builtin_amdgcn_s_barrier();       \
    __builtin_amdgcn_sched_barrier(0);  \
  } while (0)

#define VMCNT8()                                              \
  do {                                                        \
    __builtin_amdgcn_sched_barrier(0);                        \
    asm volatile("s_waitcnt vmcnt(8)" ::: "memory");          \
  } while (0)

#define VMCNT6()                                              \
  do {                                                        \
    __builtin_amdgcn_sched_barrier(0);                        \
    asm volatile("s_waitcnt vmcnt(6)" ::: "memory");          \
  } while (0)

// ---------------------------------------------------------------------------
// fp32 -> bf16 elementwise convert (vectorized)
// ---------------------------------------------------------------------------
__global__ __launch_bounds__(256) void cvt_kernel(const float* __restrict__ in,
                                                  __bf16* __restrict__ out, int n) {
  int i = (blockIdx.x * 256 + threadIdx.x) * 8;
  if (i >= n) return;
  float4 a = *reinterpret_cast<const float4*>(in + i);
  float4 b = *reinterpret_cast<const float4*>(in + i + 4);
  bf16x8 t;
  t[0] = (__bf16)a.x; t[1] = (__bf16)a.y; t[2] = (__bf16)a.z; t[3] = (__bf16)a.w;
  t[4] = (__bf16)b.x; t[5] = (__bf16)b.y; t[6] = (__bf16)b.z; t[7] = (__bf16)b.w;
  *reinterpret_cast<bf16x8*>(out + i) = t;
}

// ---------------------------------------------------------------------------
// Fused weight transpose+convert: z=0 Wq (4096 cols), z=1 Wk, z=2 Wv (1024).
// ---------------------------------------------------------------------------
__global__ __launch_bounds__(256) void tcvt3_kernel(const float* __restrict__ Wq,
                                                    const float* __restrict__ Wk,
                                                    const float* __restrict__ Wv,
                                                    __bf16* __restrict__ Wt) {
  __shared__ float t[32][33];
  int z = blockIdx.z;
  const float* in;
  __bf16* out;
  int C;
  if (z == 0)      { in = Wq; out = Wt;                         C = 4096; }
  else if (z == 1) { in = Wk; out = Wt + (size_t)4096 * 4096;   C = 1024; }
  else             { in = Wv; out = Wt + (size_t)5120 * 4096;   C = 1024; }
  if ((int)blockIdx.x * 32 >= C) return;
  int tx = threadIdx.x, ty = threadIdx.y;
  int r0 = blockIdx.y * 32, c0 = blockIdx.x * 32;
#pragma unroll
  for (int i = 0; i < 4; i++)
    t[ty + i * 8][tx] = in[(size_t)(r0 + ty + i * 8) * C + c0 + tx];
  __syncthreads();
#pragma unroll
  for (int i = 0; i < 4; i++)
    out[(size_t)(c0 + ty + i * 8) * 4096 + r0 + tx] = (__bf16)t[tx][ty + i * 8];
}

// single transpose for Wo
__global__ __launch_bounds__(256) void tcvt_f32(const float* __restrict__ in,
                                                __bf16* __restrict__ out,
                                                int R, int C) {
  __shared__ float t[32][33];
  int tx = threadIdx.x, ty = threadIdx.y;
  int r0 = blockIdx.y * 32, c0 = blockIdx.x * 32;
#pragma unroll
  for (int i = 0; i < 4; i++)
    t[ty + i * 8][tx] = in[(size_t)(r0 + ty + i * 8) * C + c0 + tx];
  __syncthreads();
#pragma unroll
  for (int i = 0; i < 4; i++)
    out[(size_t)(c0 + ty + i * 8) * R + r0 + tx] = (__bf16)t[tx][ty + i * 8];
}

// ---------------------------------------------------------------------------
// V transpose: qkv -> vt [B*NKV][HD][S], with pair-interleave permutation
// pi(16a+r) = 32*(a>>1) + 2r + (a&1) applied WITHIN each 64-kv tile (local
// col' = kv0 + 2*(tx&15) + (tx>>4), valid for kv0 % 64 in {0,32}). Writes
// still land in the same 64B segment -> coalescing unchanged. attn's P-write
// uses the same pi so PV contracts consistently.
// ---------------------------------------------------------------------------
__global__ __launch_bounds__(256) void tvt_kernel(const __bf16* __restrict__ qkv,
                                                  __bf16* __restrict__ vt) {
  __shared__ __bf16 t[32][33];
  int tx = threadIdx.x, ty = threadIdx.y;
  int z = blockIdx.z;
  int b = z >> 3, kvh = z & 7;
  int kv0 = blockIdx.y * 32, d0 = blockIdx.x * 32;
#pragma unroll
  for (int i = 0; i < 4; i++)
    t[ty + i * 8][tx] =
        qkv[(size_t)(b * S_LEN + kv0 + ty + i * 8) * QKVW + 5120 + kvh * HD + d0 + tx];
  __syncthreads();
  int cperm = kv0 + 2 * (tx & 15) + (tx >> 4);
#pragma unroll
  for (int i = 0; i < 4; i++)
    vt[((size_t)z * HD + d0 + ty + i * 8) * S_LEN + cperm] = t[tx][ty + i * 8];
}

// ---------------------------------------------------------------------------
// 256x256 GEMM, deep-pipelined (m201-aligned): constant-parity 2-tile unroll,
// uniform vmcnt(8) waits (each targets gloads issued >=4 phases prior),
// 8-12 gloads in flight. Stage schedule per tile t (par P):
//   ph0: read A0,B0(P); stage A1,B1(t+1 -> !P); vmcnt(8); BAR; M(0,0); BAR
//   ph1: read B1(P);    stage A0(t+2 -> P);               BAR; M(0,1); BAR
//   ph2: read A1(P);    stage B0(t+2 -> P);               BAR; M(1,0); M(1,1);
//        vmcnt(8); BAR
// Ledger (steady): enter ph0 with 8 outstanding [A1(t),B1(t),A0(t+1),B0(t+1)];
// ph0 +4 -> 12, vmcnt(8) retires A1(t),B1(t) (read ph1/ph2); ph1 +2, ph2 +2
// -> 12, boundary vmcnt(8) retires A0(t+1),B0(t+1) (read t+1.ph0). Region
// deaths: every stage targets a region whose last ds_read is >=1 barrier old.
// ---------------------------------------------------------------------------
template<typename CT>
__global__ __launch_bounds__(512, 2) void gemm256(const __bf16* __restrict__ A,
                                                  const __bf16* __restrict__ Bt,
                                                  CT* __restrict__ C,
                                                  int K, int ldc, int nbx) {
  __shared__ char lds[131072];
  const int tid = threadIdx.x;
  const int l = tid & 63, w = tid >> 6;
  const int lrow = l & 15, lg = l >> 4;
  const int sw = (lrow & 7) << 4;

  int nwg = gridDim.x;
  int swz = (blockIdx.x & 7) * (nwg >> 3) + (blockIdx.x >> 3);
  int bx = swz % nbx, by = swz / nbx;
  int m0 = by * 256, n0 = bx * 256;

  const int rA = w * 8 + (l >> 3);
  const int csw = ((l & 7) ^ (l >> 3)) * 8;  // inverse-swizzled source col
  const __bf16* As_[2][2];
  const __bf16* Bs_[2][2];
#pragma unroll
  for (int h = 0; h < 2; h++)
#pragma unroll
    for (int p = 0; p < 2; p++) {
      As_[h][p] = A + (size_t)(m0 + h * 128 + p * 64 + rA) * K + csw;
      Bs_[h][p] = Bt + (size_t)(n0 + h * 128 + p * 64 + rA) * K + csw;
    }

  auto stageA = [&](int par, int h, int kt) {
#pragma unroll
    for (int p = 0; p < 2; p++)
      gload16(As_[h][p] + kt * 64,
              (const __bf16*)(lds + par * 32768 + h * 16384 + p * 8192 + w * 1024));
  };
  auto stageB = [&](int par, int h, int kt) {
#pragma unroll
    for (int p = 0; p < 2; p++)
      gload16(Bs_[h][p] + kt * 64,
              (const __bf16*)(lds + 65536 + par * 32768 + h * 16384 + p * 8192 + w * 1024));
  };

  const int arbase = (w >> 2) * 64 + lrow;
  const int brbase = (w & 3) * 32 + lrow;

  bf16x8 aA[4][2];
  bf16x8 bB[2][2][2];

  auto readA = [&](int par, int ah) {
#pragma unroll
    for (int i = 0; i < 4; i++)
#pragma unroll
      for (int kk = 0; kk < 2; kk++)
        aA[i][kk] = *reinterpret_cast<const bf16x8*>(
            lds + par * 32768 + (arbase + i * 16 + ah * 128) * 128 +
            ((kk * 64 + lg * 16) ^ sw));
  };
  auto readB = [&](int par, int bh) {
#pragma unroll
    for (int j = 0; j < 2; j++)
#pragma unroll
      for (int kk = 0; kk < 2; kk++)
        bB[bh][j][kk] = *reinterpret_cast<const bf16x8*>(
            lds + 65536 + par * 32768 + (brbase + j * 16 + bh * 128) * 128 +
            ((kk * 64 + lg * 16) ^ sw));
  };

  f32x4 acc[8][4];
#pragma unroll
  for (int i = 0; i < 8; i++)
#pragma unroll
    for (int j = 0; j < 4; j++) {
      acc[i][j][0] = 0.f; acc[i][j][1] = 0.f; acc[i][j][2] = 0.f; acc[i][j][3] = 0.f;
    }

  const int NT = K >> 6;

  // prologue (FIFO order matters): A0(0),B0(0) oldest, then A1(0),B1(0),
  // A0(1),B0(1). vmcnt(8) retires exactly A0(0),B0(0).
  stageA(0, 0, 0); stageB(0, 0, 0);
  stageA(0, 1, 0); stageB(0, 1, 0);
  stageA(1, 0, 1); stageB(1, 0, 1);
  VMCNT8();
  SBAR();

#define MFMA_QUAD(AH, BH)                                                   \
  __builtin_amdgcn_s_setprio(1);                                            \
  _Pragma("unroll") for (int i4 = 0; i4 < 4; i4++)                          \
      _Pragma("unroll") for (int j2 = 0; j2 < 2; j2++)                      \
          _Pragma("unroll") for (int kk = 0; kk < 2; kk++)                  \
              acc[(AH)*4 + i4][(BH)*2 + j2] =                               \
                  mfma16(aA[i4][kk], bB[BH][j2][kk], acc[(AH)*4 + i4][(BH)*2 + j2]); \
  __builtin_amdgcn_s_setprio(0);

#define GTILE256(PAR, TT)                                                   \
  {                                                                         \
    const int t1n = ((TT) + 1 < NT) ? (TT) + 1 : 0;                         \
    const int t2n = ((TT) + 2 < NT) ? (TT) + 2 : 0;                         \
    readA(PAR, 0);                                                          \
    readB(PAR, 0);                                                          \
    stageA(PAR ^ 1, 1, t1n);                                                \
    stageB(PAR ^ 1, 1, t1n);                                                \
    VMCNT8();                                                               \
    SBAR();                                                                 \
    MFMA_QUAD(0, 0);                                                        \
    SBAR();                                                                 \
    readB(PAR, 1);                                                          \
    stageA(PAR, 0, t2n);                                                    \
    SBAR();                                                                 \
    MFMA_QUAD(0, 1);                                                        \
    SBAR();                                                                 \
    readA(PAR, 1);                                                          \
    stageB(PAR, 0, t2n);                                                    \
    SBAR();                                                                 \
    MFMA_QUAD(1, 0);                                                        \
    MFMA_QUAD(1, 1);                                                        \
    VMCNT8();                                                               \
    SBAR();                                                                 \
  }

  for (int t = 0; t < NT; t += 2) {
    GTILE256(0, t);
    GTILE256(1, t + 1);
  }
#undef GTILE256
#undef MFMA_QUAD

#pragma unroll
  for (int i = 0; i < 8; i++) {
    int row = m0 + (w >> 2) * 64 + (i & 3) * 16 + (i >> 2) * 128 + lg * 4;
#pragma unroll
    for (int j = 0; j < 4; j++) {
      int col = n0 + (w & 3) * 32 + (j & 1) * 16 + (j >> 1) * 128 + lrow;
#pragma unroll
      for (int jj = 0; jj < 4; jj++)
        C[(size_t)(row + jj) * ldc + col] = (CT)acc[i][j][jj];
    }
  }
}

// ---------------------------------------------------------------------------
// 256x128 GEMM, deep-pipelined analog. Per tile t (par P):
//   ph0: read A0(P),B(P); stage A1(t+1 -> !P); vmcnt(6); BAR; M0; BAR
//   ph1: read A1(P); stage B(t+2 -> P), A0(t+2 -> P); BAR; M1; vmcnt(6); BAR
// Ledger (steady): enter ph0 with 6 [A1(t),B(t+1),A0(t+1)]; +2 -> 8, vmcnt(6)
// retires A1(t) (read ph1); ph1 +4 -> 10, vmcnt(6) retires B(t+1),A0(t+1)
// (read t+1.ph0). B now staged 2 tiles ahead (into P-region dead after ph0).
// ---------------------------------------------------------------------------
template<typename CT>
__global__ __launch_bounds__(512, 2) void gemm128(const __bf16* __restrict__ A,
                                                  const __bf16* __restrict__ Bt,
                                                  CT* __restrict__ C,
                                                  int K, int ldc, int nbx) {
  __shared__ char lds[98304];
  const int tid = threadIdx.x;
  const int l = tid & 63, w = tid >> 6;
  const int lrow = l & 15, lg = l >> 4;
  const int sw = (lrow & 7) << 4;

  int nwg = gridDim.x;
  int swz = (blockIdx.x & 7) * (nwg >> 3) + (blockIdx.x >> 3);
  int bx = swz % nbx, by = swz / nbx;
  int m0 = by * 256, n0 = bx * 128;

  const int rA = w * 8 + (l >> 3);
  const int csw = ((l & 7) ^ (l >> 3)) * 8;
  const __bf16* As_[2][2];
  const __bf16* Bs_[2];
#pragma unroll
  for (int h = 0; h < 2; h++)
#pragma unroll
    for (int p = 0; p < 2; p++)
      As_[h][p] = A + (size_t)(m0 + h * 128 + p * 64 + rA) * K + csw;
#pragma unroll
  for (int p = 0; p < 2; p++)
    Bs_[p] = Bt + (size_t)(n0 + p * 64 + rA) * K + csw;

  auto stageA = [&](int par, int h, int kt) {
#pragma unroll
    for (int p = 0; p < 2; p++)
      gload16(As_[h][p] + kt * 64,
              (const __bf16*)(lds + par * 32768 + h * 16384 + p * 8192 + w * 1024));
  };
  auto stageB = [&](int par, int kt) {
#pragma unroll
    for (int p = 0; p < 2; p++)
      gload16(Bs_[p] + kt * 64,
              (const __bf16*)(lds + 65536 + par * 16384 + p * 8192 + w * 1024));
  };

  const int arbase = (w >> 2) * 64 + lrow;
  const int brbase = (w & 3) * 32 + lrow;

  bf16x8 aA[4][2];
  bf16x8 bB[2][2];

  auto readA = [&](int par, int ah) {
#pragma unroll
    for (int i = 0; i < 4; i++)
#pragma unroll
      for (int kk = 0; kk < 2; kk++)
        aA[i][kk] = *reinterpret_cast<const bf16x8*>(
            lds + par * 32768 + (arbase + i * 16 + ah * 128) * 128 +
            ((kk * 64 + lg * 16) ^ sw));
  };
  auto readB = [&](int par) {
#pragma unroll
    for (int j = 0; j < 2; j++)
#pragma unroll
      for (int kk = 0; kk < 2; kk++)
        bB[j][kk] = *reinterpret_cast<const bf16x8*>(
            lds + 65536 + par * 16384 + (brbase + j * 16) * 128 +
            ((kk * 64 + lg * 16) ^ sw));
  };

  f32x4 acc[8][2];
#pragma unroll
  for (int i = 0; i < 8; i++)
#pragma unroll
    for (int j = 0; j < 2; j++) {
      acc[i][j][0] = 0.f; acc[i][j][1] = 0.f; acc[i][j][2] = 0.f; acc[i][j][3] = 0.f;
    }

  const int NT = K >> 6;

  // prologue FIFO: A0(0),B(0) oldest; then A1(0),B(1),A0(1). vmcnt(6)
  // retires A0(0),B(0).
  stageA(0, 0, 0); stageB(0, 0);
  stageA(0, 1, 0); stageB(1, 1); stageA(1, 0, 1);
  VMCNT6();
  SBAR();

#define MFMA_HALF(AH)                                                        \
  __builtin_amdgcn_s_setprio(1);                                             \
  _Pragma("unroll") for (int i4 = 0; i4 < 4; i4++)                           \
      _Pragma("unroll") for (int j2 = 0; j2 < 2; j2++)                       \
          _Pragma("unroll") for (int kk = 0; kk < 2; kk++)                   \
              acc[(AH)*4 + i4][j2] =                                         \
                  mfma16(aA[i4][kk], bB[j2][kk], acc[(AH)*4 + i4][j2]);      \
  __builtin_amdgcn_s_setprio(0);

#define GTILE128(PAR, TT)                                                    \
  {                                                                          \
    const int t1n = ((TT) + 1 < NT) ? (TT) + 1 : 0;                          \
    const int t2n = ((TT) + 2 < NT) ? (TT) + 2 : 0;                          \
    readA(PAR, 0);                                                           \
    readB(PAR);                                                              \
    stageA(PAR ^ 1, 1, t1n);                                                 \
    VMCNT6();                                                                \
    SBAR();                                                                  \
    MFMA_HALF(0);                                                            \
    SBAR();                                                                  \
    readA(PAR, 1);                                                           \
    stageB(PAR, t2n);                                                        \
    stageA(PAR, 0, t2n);                                                     \
    SBAR();                                                                  \
    MFMA_HALF(1);                                                            \
    VMCNT6();                                                                \
    SBAR();                                                                  \
  }

  for (int t = 0; t < NT; t += 2) {
    GTILE128(0, t);
    GTILE128(1, t + 1);
  }
#undef GTILE128
#undef MFMA_HALF

#pragma unroll
  for (int i = 0; i < 8; i++) {
    int row = m0 + (w >> 2) * 64 + (i & 3) * 16 + (i >> 2) * 128 + lg * 4;
#pragma unroll
    for (int j = 0; j < 2; j++) {
      int col = n0 + (w & 3) * 32 + j * 16 + lrow;
#pragma unroll
      for (int jj = 0; jj < 4; jj++)
        C[(size_t)(row + jj) * ldc + col] = (CT)acc[i][j][jj];
    }
  }
}

// ---------------------------------------------------------------------------
// RoPE, in-place on fused qkv buffer, vectorized.
// ---------------------------------------------------------------------------
__global__ __launch_bounds__(256) void rope_kernel(__bf16* __restrict__ qkv,
                                                   const int* __restrict__ pos) {
  int row = blockIdx.x;
  int t = threadIdx.x;
  float p = (float)pos[row];
  __bf16* rbase = qkv + (size_t)row * QKVW;

  {
    int head = t >> 3, chunk = t & 7;
    __bf16* base = rbase + head * HD + chunk * 8;
    bf16x8 x1 = *reinterpret_cast<const bf16x8*>(base);
    bf16x8 x2 = *reinterpret_cast<const bf16x8*>(base + 64);
    bf16x8 o1, o2;
#pragma unroll
    for (int e = 0; e < 8; e++) {
      float ang = p * exp2f(-0.20762050f * (float)(chunk * 8 + e));
      float s, c;
      __sincosf(ang, &s, &c);
      float a = (float)x1[e], b2 = (float)x2[e];
      o1[e] = (__bf16)(a * c - b2 * s);
      o2[e] = (__bf16)(b2 * c + a * s);
    }
    *reinterpret_cast<bf16x8*>(base) = o1;
    *reinterpret_cast<bf16x8*>(base + 64) = o2;
  }
  if (t < 64) {
    int head = t >> 3, chunk = t & 7;
    __bf16* base = rbase + 4096 + head * HD + chunk * 8;
    bf16x8 x1 = *reinterpret_cast<const bf16x8*>(base);
    bf16x8 x2 = *reinterpret_cast<const bf16x8*>(base + 64);
    bf16x8 o1, o2;
#pragma unroll
    for (int e = 0; e < 8; e++) {
      float ang = p * exp2f(-0.20762050f * (float)(chunk * 8 + e));
      float s, c;
      __sincosf(ang, &s, &c);
      float a = (float)x1[e], b2 = (float)x2[e];
      o1[e] = (__bf16)(a * c - b2 * s);
      o2[e] = (__bf16)(b2 * c + a * s);
    }
    *reinterpret_cast<bf16x8*>(base) = o1;
    *reinterpret_cast<bf16x8*>(base + 64) = o2;
  }
}

// ---------------------------------------------------------------------------
// Flash attention, causal, GQA. 512 blocks (2/CU co-resident), heavy-first.
// Guarded-reduce online softmax (R10 structure). P stored in pi-permuted kv
// order (pairs (kv, kv+16) adjacent) so P-writes are 16 packed b32 instead of
// 32 scalar b16; V arrives pre-permuted from tvt, so PV contraction order is
// consistent (sum over permuted kv == sum over kv).
// ---------------------------------------------------------------------------
__global__ __launch_bounds__(512) void attn_kernel(const __bf16* __restrict__ qkv,
                                                   const __bf16* __restrict__ vt,
                                                   __bf16* __restrict__ out) {
  __shared__ __bf16 Ks[64 * 128];      // [kv][d], swizzled, 16 KB
  __shared__ __bf16 Vs[128 * 64];      // [d][kv'], swizzled, 16 KB
  __shared__ __bf16 Ps[8][32][68];     // per-wave P (kv'-order), padded, 34 KB

  int tid = threadIdx.x;
  int l = tid & 63, w = tid >> 6;
  int bid = blockIdx.x;
  int qblk = 7 - (bid >> 6);           // heavy blocks first
  int rem = bid & 63;
  int h = rem & 31, b = rem >> 5;
  int kvh = h >> 2;
  int q0w = qblk * 256 + w * 32;
  int lrow = l & 15, lg = l >> 4;
  int sw = (lrow & 7) << 4;
  const float SCL = 0.08838834764831845f * 1.4426950408889634f;  // 1/sqrt(128)*log2e

  const __bf16* kbase = qkv + (size_t)(b * S_LEN) * QKVW + 4096 + kvh * HD;
  const __bf16* vbase = vt + ((size_t)(b * NKV + kvh) * HD) * S_LEN;

  int krow = tid >> 3;
  int kslot = (tid & 7) * 2;
  int vrow = tid >> 2;
  int vslot = (tid & 3) * 2;
  char* KsB = (char*)Ks;
  char* VsB = (char*)Vs;
  int koff0 = krow * 256 + ((kslot * 16) ^ ((krow & 7) << 4));
  int koff1 = krow * 256 + (((kslot + 1) * 16) ^ ((krow & 7) << 4));
  int voff0 = vrow * 128 + ((vslot * 16) ^ ((vrow & 7) << 4));
  int voff1 = vrow * 128 + (((vslot + 1) * 16) ^ ((vrow & 7) << 4));
  const __bf16* kg = kbase + (size_t)krow * QKVW + kslot * 8;
  const __bf16* vg = vbase + (size_t)vrow * S_LEN + vslot * 8;

  // Q fragments, pre-scaled
  bf16x8 qf[2][4];
#pragma unroll
  for (int mi = 0; mi < 2; mi++) {
    const __bf16* qp = qkv + (size_t)(b * S_LEN + q0w + mi * 16 + lrow) * QKVW + h * HD + lg * 8;
#pragma unroll
    for (int kk = 0; kk < 4; kk++) {
      bf16x8 t = *reinterpret_cast<const bf16x8*>(qp + kk * 32);
#pragma unroll
      for (int e = 0; e < 8; e++) t[e] = (__bf16)((float)t[e] * SCL);
      qf[mi][kk] = t;
    }
  }

  f32x4 ov[2][8];
#pragma unroll
  for (int mi = 0; mi < 2; mi++)
#pragma unroll
    for (int n = 0; n < 8; n++) {
      ov[mi][n][0] = 0.f; ov[mi][n][1] = 0.f; ov[mi][n][2] = 0.f; ov[mi][n][3] = 0.f;
    }
  float m[2][4], ssum[2][4];
#pragma unroll
  for (int mi = 0; mi < 2; mi++)
#pragma unroll
    for (int jj = 0; jj < 4; jj++) { m[mi][jj] = -3.0e38f; ssum[mi][jj] = 0.f; }

  int nt = 4 * qblk + 4;
  bf16x8 kr0, kr1, vr0, vr1;

  kr0 = *reinterpret_cast<const bf16x8*>(kg);
  kr1 = *reinterpret_cast<const bf16x8*>(kg + 8);
  vr0 = *reinterpret_cast<const bf16x8*>(vg);
  vr1 = *reinterpret_cast<const bf16x8*>(vg + 8);
  *reinterpret_cast<bf16x8*>(KsB + koff0) = kr0;
  *reinterpret_cast<bf16x8*>(KsB + koff1) = kr1;
  *reinterpret_cast<bf16x8*>(VsB + voff0) = vr0;
  *reinterpret_cast<bf16x8*>(VsB + voff1) = vr1;
  __syncthreads();

  for (int t = 0;; t++) {
    int kv0 = t * 64;
    bool more = (t + 1 < nt);
    if (more) {
      int kvn = kv0 + 64;
      kr0 = *reinterpret_cast<const bf16x8*>(kg + (size_t)kvn * QKVW);
      kr1 = *reinterpret_cast<const bf16x8*>(kg + (size_t)kvn * QKVW + 8);
      vr0 = *reinterpret_cast<const bf16x8*>(vg + kvn);
      vr1 = *reinterpret_cast<const bf16x8*>(vg + kvn + 8);
    }

    bool active = (kv0 <= q0w + 31);
    if (active) {
      f32x4 sc[2][4];
#pragma unroll
      for (int mi = 0; mi < 2; mi++)
#pragma unroll
        for (int c = 0; c < 4; c++) {
          sc[mi][c][0] = 0.f; sc[mi][c][1] = 0.f; sc[mi][c][2] = 0.f; sc[mi][c][3] = 0.f;
        }
#pragma unroll
      for (int c = 0; c < 4; c++) {
        int rb = (c * 16 + lrow) * 256;
#pragma unroll
        for (int kk = 0; kk < 4; kk++) {
          bf16x8 kf = *reinterpret_cast<const bf16x8*>(KsB + rb + ((kk * 64 + lg * 16) ^ sw));
          sc[0][c] = mfma16(qf[0][kk], kf, sc[0][c]);
          sc[1][c] = mfma16(qf[1][kk], kf, sc[1][c]);
        }
      }

      // causal mask
      bool bound = (kv0 + 64 > q0w);
      if (bound) {
#pragma unroll
        for (int mi = 0; mi < 2; mi++)
#pragma unroll
          for (int jj = 0; jj < 4; jj++) {
            int qidx = q0w + mi * 16 + lg * 4 + jj;
            if (kv0 + lrow > qidx)      sc[mi][0][jj] = -3.0e38f;
            if (kv0 + 16 + lrow > qidx) sc[mi][1][jj] = -3.0e38f;
            if (kv0 + 32 + lrow > qidx) sc[mi][2][jj] = -3.0e38f;
            if (kv0 + 48 + lrow > qidx) sc[mi][3][jj] = -3.0e38f;
          }
      }

      // per-lane growth check (cheap); reduce+rescale only when needed
      float lm[2][4];
      bool lanegrow = false;
#pragma unroll
      for (int mi = 0; mi < 2; mi++)
#pragma unroll
        for (int jj = 0; jj < 4; jj++) {
          lm[mi][jj] = fmaxf(fmaxf(sc[mi][0][jj], sc[mi][1][jj]),
                             fmaxf(sc[mi][2][jj], sc[mi][3][jj]));
          lanegrow |= (lm[mi][jj] > m[mi][jj] + 8.0f);
        }

      if (__any(lanegrow)) {
        // rare slow path: full row-max reduce, update m, rescale ov & ssum
        float es[2][4];
#pragma unroll
        for (int mi = 0; mi < 2; mi++)
#pragma unroll
          for (int jj = 0; jj < 4; jj++) {
            float r = lm[mi][jj];
            r = fmaxf(r, __shfl_xor(r, 1));
            r = fmaxf(r, __shfl_xor(r, 2));
            r = fmaxf(r, __shfl_xor(r, 4));
            r = fmaxf(r, __shfl_xor(r, 8));
            float mo = m[mi][jj];
            bool grow = (r > mo + 8.0f);
            float mn = grow ? r : mo;
            float e = grow ? exp2f(mo - r) : 1.0f;
            es[mi][jj] = e;
            m[mi][jj] = mn;
            ssum[mi][jj] *= e;
          }
#pragma unroll
        for (int mi = 0; mi < 2; mi++)
#pragma unroll
          for (int n = 0; n < 8; n++)
#pragma unroll
            for (int jj = 0; jj < 4; jj++) ov[mi][n][jj] *= es[mi][jj];
      }

      // single exp2 / packed P-write path. Storage col' = pi(kv):
      // (p0,p1) -> cols (2*lrow, 2*lrow+1); (p2,p3) -> (32+2*lrow, +1).
#pragma unroll
      for (int mi = 0; mi < 2; mi++)
#pragma unroll
        for (int jj = 0; jj < 4; jj++) {
          float mn = m[mi][jj];
          float p0 = exp2f(sc[mi][0][jj] - mn), p1 = exp2f(sc[mi][1][jj] - mn);
          float p2 = exp2f(sc[mi][2][jj] - mn), p3 = exp2f(sc[mi][3][jj] - mn);
          ssum[mi][jj] += (p0 + p1) + (p2 + p3);
          int pr = mi * 16 + lg * 4 + jj;
          union { __bf16 hh[2]; unsigned int u; } a01, a23;
          a01.hh[0] = (__bf16)p0; a01.hh[1] = (__bf16)p1;
          a23.hh[0] = (__bf16)p2; a23.hh[1] = (__bf16)p3;
          *reinterpret_cast<unsigned int*>(&Ps[w][pr][2 * lrow]) = a01.u;
          *reinterpret_cast<unsigned int*>(&Ps[w][pr][32 + 2 * lrow]) = a23.u;
        }

#pragma unroll
      for (int kvs = 0; kvs < 2; kvs++) {
        bf16x8 pf0 = *reinterpret_cast<const bf16x8*>(&Ps[w][lrow][kvs * 32 + lg * 8]);
        bf16x8 pf1 = *reinterpret_cast<const bf16x8*>(&Ps[w][16 + lrow][kvs * 32 + lg * 8]);
#pragma unroll
        for (int n = 0; n < 8; n++) {
          bf16x8 vf = *reinterpret_cast<const bf16x8*>(
              VsB + (n * 16 + lrow) * 128 + ((kvs * 64 + lg * 16) ^ sw));
          ov[0][n] = mfma16(pf0, vf, ov[0][n]);
          ov[1][n] = mfma16(pf1, vf, ov[1][n]);
        }
      }
    }

    if (!more) break;
    __syncthreads();
    *reinterpret_cast<bf16x8*>(KsB + koff0) = kr0;
    *reinterpret_cast<bf16x8*>(KsB + koff1) = kr1;
    *reinterpret_cast<bf16x8*>(VsB + voff0) = vr0;
    *reinterpret_cast<bf16x8*>(VsB + voff1) = vr1;
    __syncthreads();
  }

  float rinv[2][4];
#pragma unroll
  for (int mi = 0; mi < 2; mi++)
#pragma unroll
    for (int jj = 0; jj < 4; jj++) {
      float s = ssum[mi][jj];
      s += __shfl_xor(s, 1);
      s += __shfl_xor(s, 2);
      s += __shfl_xor(s, 4);
      s += __shfl_xor(s, 8);
      rinv[mi][jj] = 1.0f / s;
    }
#pragma unroll
  for (int mi = 0; mi < 2; mi++)
#pragma unroll
    for (int n = 0; n < 8; n++)
#pragma unroll
      for (int jj = 0; jj < 4; jj++) {
        out[(size_t)(b * S_LEN + q0w + mi * 16 + lg * 4 + jj) * HIDDEN + h * HD + n * 16 + lrow] =
            (__bf16)(ov[mi][n][jj] * rinv[mi][jj]);
      }
}

// ---------------------------------------------------------------------------
// Workspace layout (bytes), total 142606336:
//   h_bf / a_buf (aliased) @ 0          33554432   bf16 [4096][4096]
//   Wt (qkv^T, later Wo^T) @ 33554432   50331648   bf16 [6144][4096]
//   qkv_buf                @ 83886080   50331648   bf16 [4096][6144]
//   vt_buf                 @ 134217728   8388608   bf16 [16][128][2048]
// ---------------------------------------------------------------------------
extern "C" void kernel_launch(void* const* d_in, const int* in_sizes, int n_in,
                              void* d_out, int out_size, void* d_ws, size_t ws_size,
                              hipStream_t stream) {
  const float* hidden = (const float*)d_in[0];
  const int* posids   = (const int*)d_in[1];
  const float* Wq     = (const float*)d_in[2];
  const float* Wk     = (const float*)d_in[3];
  const float* Wv     = (const float*)d_in[4];
  const float* Wo     = (const float*)d_in[5];
  float* out = (float*)d_out;

  char* ws = (char*)d_ws;
  __bf16* h_bf    = (__bf16*)(ws + 0);
  __bf16* a_buf   = h_bf;  // aliased: h last read by QKV GEMMs, before attn writes
  __bf16* Wt      = (__bf16*)(ws + 33554432);
  __bf16* qkv_buf = (__bf16*)(ws + 83886080);
  __bf16* vt_buf  = (__bf16*)(ws + 134217728);

  dim3 b256(256), b328(32, 8), b512(512);

  // 1. hidden -> bf16
  cvt_kernel<<<dim3(MROWS * HIDDEN / (256 * 8)), b256, 0, stream>>>(hidden, h_bf, MROWS * HIDDEN);

  // 2. fused weight transpose: Wt = [Wq^T ; Wk^T ; Wv^T]  [6144][4096]
  tcvt3_kernel<<<dim3(128, 128, 3), b328, 0, stream>>>(Wq, Wk, Wv, Wt);

  // 3a. QKV main: cols [0,4096) via 256^2 tiles -> 256 blocks (1 round)
  gemm256<__bf16><<<dim3(256), b512, 0, stream>>>(
      h_bf, Wt, qkv_buf, HIDDEN, QKVW, 4096 / 256);
  // 3b. QKV tail: cols [4096,6144) via 256x128 tiles -> 256 blocks
  gemm128<__bf16><<<dim3(256), b512, 0, stream>>>(
      h_bf, Wt + (size_t)4096 * 4096, qkv_buf + 4096, HIDDEN, QKVW, 2048 / 128);

  // 4. RoPE on q,k (in fused buffer), vectorized
  rope_kernel<<<dim3(MROWS), b256, 0, stream>>>(qkv_buf, posids);

  // 5. V^T (pi-permuted kv within each 64-tile)
  tvt_kernel<<<dim3(HD / 32, S_LEN / 32, BATCH * NKV), b328, 0, stream>>>(qkv_buf, vt_buf);

  // 6. attention -> a_buf  (512 blocks, heavy-first, 2 blocks/CU)
  attn_kernel<<<dim3(8 * NH * BATCH), b512, 0, stream>>>(qkv_buf, vt_buf, a_buf);

  // 7. Wo^T (reuse Wt)
  tcvt_f32<<<dim3(HIDDEN / 32, HIDDEN / 32), b328, 0, stream>>>(Wo, Wt, HIDDEN, HIDDEN);

  // 8. out = a @ Wo  (fp32 out; 256 blocks = 1 balanced round)
  gemm256<float><<<dim3(256), b512, 0, stream>>>(
      a_buf, Wt, out, HIDDEN, HIDDEN, HIDDEN / 256);
}